// Round 14
// baseline (329.179 us; speedup 1.0000x reference)
//
#include <hip/hip_runtime.h>
#include <math.h>

#define Bh 8
#define Lh 64
#define Dh 768
#define Fh 50
#define Ph 49
#define Ah 49
#define Nh 20000
#define Ch 36
#define CAP 2048
#define NCH 8
#define CUTE 2e-6f

typedef __bf16 bf16x8 __attribute__((ext_vector_type(8)));
typedef float f32x4 __attribute__((ext_vector_type(4)));
union U { uint4 u; bf16x8 v; };

__device__ __forceinline__ void cvt2(float a0, float a1, unsigned& h, unsigned& l) {
    unsigned u0 = __float_as_uint(a0), u1 = __float_as_uint(a1);
    unsigned h0 = u0 & 0xFFFF0000u, h1 = u1 & 0xFFFF0000u;
    h = (h0 >> 16) | h1;
    float l0 = a0 - __uint_as_float(h0);
    float l1 = a1 - __uint_as_float(h1);
    l = (__float_as_uint(l0) >> 16) | (__float_as_uint(l1) & 0xFFFF0000u);
}

__device__ __forceinline__ void cvt8(float4 p, float4 q, bf16x8& h8, bf16x8& l8) {
    U h, l;
    cvt2(p.x, p.y, h.u.x, l.u.x);
    cvt2(p.z, p.w, h.u.y, l.u.y);
    cvt2(q.x, q.y, h.u.z, l.u.z);
    cvt2(q.z, q.w, h.u.w, l.u.w);
    h8 = h.v; l8 = l.v;
}

__device__ __forceinline__ float dec_max(unsigned u) {
    if (u == 0u) return 0.f;
    return (u & 0x80000000u) ? __uint_as_float(u ^ 0x80000000u) : __uint_as_float(~u);
}

// sum the 8 Spart chunks for (row, d..d+3)
__device__ __forceinline__ float4 sumS(const float* __restrict__ Spart, int rowg, int d) {
    float4 s = {0.f, 0.f, 0.f, 0.f};
#pragma unroll
    for (int ch = 0; ch < NCH; ++ch) {
        float4 v = *(const float4*)&Spart[((size_t)rowg * NCH + ch) * Dh + d];
        s.x += v.x; s.y += v.y; s.z += v.z; s.w += v.w;
    }
    return s;
}

// ---- prep: [0,576) W frags | [576,723) Wf2T | 723 zero | [724,1012) candidate LN ----
__global__ __launch_bounds__(256) void k_prep(const float* __restrict__ Wg,
                                              const float* __restrict__ Wt,
                                              const float* __restrict__ Wf2,
                                              const float* __restrict__ cands,
                                              const float* __restrict__ W_cand,
                                              const float* __restrict__ b_cand,
                                              const float* __restrict__ ln_g,
                                              const float* __restrict__ ln_b,
                                              uint4* __restrict__ WgH, uint4* __restrict__ WgL,
                                              uint4* __restrict__ WtH, uint4* __restrict__ WtL,
                                              float* __restrict__ Wf2T,
                                              float* __restrict__ cn,
                                              unsigned* __restrict__ m_u,
                                              float* __restrict__ den,
                                              int* __restrict__ cnt) {
    __shared__ float cv[Dh];
    __shared__ float red[8];
    __shared__ float mu_s, rs_s;
    int bx = blockIdx.x, tid = threadIdx.x;
    if (bx < 576) {
        bool g = bx < 288;
        int gid = (g ? bx : bx - 288) * 256 + tid;   // < 73728
        const float* W = g ? Wg : Wt;
        int l = gid & 63;
        int rest = gid >> 6;
        int ct = rest % 48, ks = rest / 48;
        const float* src = W + (size_t)(ct * 16 + (l & 15)) * Dh + ks * 32 + (l >> 4) * 8;
        float4 p = *(const float4*)src;
        float4 q = *(const float4*)(src + 4);
        U h, lo;
        cvt2(p.x, p.y, h.u.x, lo.u.x);
        cvt2(p.z, p.w, h.u.y, lo.u.y);
        cvt2(q.x, q.y, h.u.z, lo.u.z);
        cvt2(q.z, q.w, h.u.w, lo.u.w);
        if (g) { WgH[gid] = h.u; WgL[gid] = lo.u; }
        else   { WtH[gid] = h.u; WtL[gid] = lo.u; }
    } else if (bx < 723) {
        int i = (bx - 576) * 256 + tid;              // < 37632 = 768*49 exact
        int d = i / 49, j = i - d * 49;
        Wf2T[j * Dh + d] = Wf2[i];
    } else if (bx == 723) {
        for (int i = tid; i < Bh * Ch; i += 256) { m_u[i] = 0u; den[i] = 0.f; cnt[i] = 0; }
    } else {
        // candidate encoder LN -> cn[b*Ch+c][d]
        int idx = bx - 724;               // [0,288)
        int b = idx / Ch, c = idx % Ch;
        float cx = cands[(b * Ch + c) * 2 + 0], cy = cands[(b * Ch + c) * 2 + 1];
        for (int d = tid; d < Dh; d += 256)
            cv[d] = W_cand[d * 2] * cx + W_cand[d * 2 + 1] * cy + b_cand[d];
        __syncthreads();
        float ls = 0.f;
        for (int d = tid; d < Dh; d += 256) ls += cv[d];
        for (int m = 32; m; m >>= 1) ls += __shfl_xor(ls, m);
        if ((tid & 63) == 0) red[tid >> 6] = ls;
        __syncthreads();
        if (tid == 0) mu_s = (red[0] + red[1] + red[2] + red[3]) * (1.f / Dh);
        __syncthreads();
        float mu = mu_s;
        float lv = 0.f;
        for (int d = tid; d < Dh; d += 256) { float t = cv[d] - mu; lv += t * t; }
        for (int m = 32; m; m >>= 1) lv += __shfl_xor(lv, m);
        if ((tid & 63) == 0) red[4 + (tid >> 6)] = lv;
        __syncthreads();
        if (tid == 0) rs_s = rsqrtf((red[4] + red[5] + red[6] + red[7]) * (1.f / Dh) + 1e-12f);
        __syncthreads();
        float rs = rs_s;
#pragma unroll
        for (int j = 0; j < 3; ++j) {
            int d = tid + j * 256;
            cn[(size_t)(b * Ch + c) * Dh + d] = (cv[d] - mu) * rs * ln_g[d] + ln_b[d];
        }
    }
}

// ---------------- tf: [0,48) text MFMA GEMM | [48,448) frames path ----------------
__global__ __launch_bounds__(256) void k_tf(const float* __restrict__ lang,
                                            const uint4* __restrict__ WtH,
                                            const uint4* __restrict__ WtL,
                                            const float* __restrict__ bt,
                                            const float* __restrict__ frames,
                                            const float* __restrict__ lang_cls,
                                            const float* __restrict__ W_in,
                                            const float* __restrict__ W_out,
                                            const float* __restrict__ Wf2T,
                                            const float* __restrict__ b_fc2,
                                            float* __restrict__ text,
                                            float* __restrict__ out) {
    __shared__ float smem[8192];
    int bx = blockIdx.x;
    int tid = threadIdx.x;

    if (bx < 48) {
        float (*lds)[4096] = (float(*)[4096])smem;
        int wv = tid >> 6, l = tid & 63;
        int dt = bx % 12;
        int m0 = (bx / 12) * 128;

        const uint4* pbh = WtH + (size_t)dt * 256 + l;
        const uint4* pbl = WtL + (size_t)dt * 256 + l;

        const float* srcA[4]; int dA[4];
#pragma unroll
        for (int r = 0; r < 4; ++r) {
            int s = r * 256 + tid, row = s >> 3, pos = s & 7;
            srcA[r] = lang + (size_t)(m0 + row) * Dh + pos * 4;
            dA[r] = row * 32 + ((pos ^ (row & 7)) << 2);
        }
        int lm = l & 15, lh = l >> 4, r7 = lm & 7;
        int oA[2][2];
#pragma unroll
        for (int rt = 0; rt < 2; ++rt)
#pragma unroll
            for (int j = 0; j < 2; ++j)
                oA[rt][j] = (wv * 32 + rt * 16 + lm) * 32 + (((lh * 2 + j) ^ r7) << 2);

        {
            float4 v0 = *(const float4*)srcA[0];
            float4 v1 = *(const float4*)srcA[1];
            float4 v2 = *(const float4*)srcA[2];
            float4 v3 = *(const float4*)srcA[3];
            *(float4*)&lds[0][dA[0]] = v0;
            *(float4*)&lds[0][dA[1]] = v1;
            *(float4*)&lds[0][dA[2]] = v2;
            *(float4*)&lds[0][dA[3]] = v3;
        }
        __syncthreads();

        f32x4 acc[2][4];
#pragma unroll
        for (int i = 0; i < 2; ++i)
#pragma unroll
            for (int j = 0; j < 4; ++j) acc[i][j] = (f32x4){0.f, 0.f, 0.f, 0.f};

        for (int t = 0; t < 24; ++t) {
            int cur = t & 1;
            float4 p0, p1, p2, p3;
            bool pf = (t < 23);
            if (pf) {
                int o = (t + 1) * 32;
                p0 = *(const float4*)(srcA[0] + o);
                p1 = *(const float4*)(srcA[1] + o);
                p2 = *(const float4*)(srcA[2] + o);
                p3 = *(const float4*)(srcA[3] + o);
            }
            uint4 bh0 = pbh[t * 3072 +   0], bh1 = pbh[t * 3072 +  64];
            uint4 bh2 = pbh[t * 3072 + 128], bh3 = pbh[t * 3072 + 192];
            uint4 bl0 = pbl[t * 3072 +   0], bl1 = pbl[t * 3072 +  64];
            uint4 bl2 = pbl[t * 3072 + 128], bl3 = pbl[t * 3072 + 192];

            const float* L = lds[cur];
            float4 a00 = *(const float4*)&L[oA[0][0]];
            float4 a01 = *(const float4*)&L[oA[0][1]];
            float4 a10 = *(const float4*)&L[oA[1][0]];
            float4 a11 = *(const float4*)&L[oA[1][1]];
            bf16x8 ah0, al0, ah1, al1;
            cvt8(a00, a01, ah0, al0);
            cvt8(a10, a11, ah1, al1);

            uint4 bhu[4] = {bh0, bh1, bh2, bh3};
            uint4 blu[4] = {bl0, bl1, bl2, bl3};
#pragma unroll
            for (int ct = 0; ct < 4; ++ct) {
                U ubh, ubl; ubh.u = bhu[ct]; ubl.u = blu[ct];
                bf16x8 bh = ubh.v, bl = ubl.v;
                acc[0][ct] = __builtin_amdgcn_mfma_f32_16x16x32_bf16(ah0, bh, acc[0][ct], 0, 0, 0);
                acc[0][ct] = __builtin_amdgcn_mfma_f32_16x16x32_bf16(al0, bh, acc[0][ct], 0, 0, 0);
                acc[0][ct] = __builtin_amdgcn_mfma_f32_16x16x32_bf16(ah0, bl, acc[0][ct], 0, 0, 0);
                acc[1][ct] = __builtin_amdgcn_mfma_f32_16x16x32_bf16(ah1, bh, acc[1][ct], 0, 0, 0);
                acc[1][ct] = __builtin_amdgcn_mfma_f32_16x16x32_bf16(al1, bh, acc[1][ct], 0, 0, 0);
                acc[1][ct] = __builtin_amdgcn_mfma_f32_16x16x32_bf16(ah1, bl, acc[1][ct], 0, 0, 0);
            }
            if (pf) {
                float* D = lds[cur ^ 1];
                *(float4*)&D[dA[0]] = p0;
                *(float4*)&D[dA[1]] = p1;
                *(float4*)&D[dA[2]] = p2;
                *(float4*)&D[dA[3]] = p3;
            }
            __syncthreads();
        }

#pragma unroll
        for (int rt = 0; rt < 2; ++rt) {
#pragma unroll
            for (int r = 0; r < 4; ++r) {
                int row = m0 + wv * 32 + rt * 16 + lh * 4 + r;
#pragma unroll
                for (int ct = 0; ct < 4; ++ct) {
                    int d = dt * 64 + ct * 16 + lm;
                    text[(size_t)row * Dh + d] = acc[rt][ct][r] + bt[d];
                }
            }
        }
    } else {
        int fid = bx - 48;
        int b = fid / Fh, f = fid % Fh;
        float* fr = smem;            // 2401
        float* tg = smem + 2401;     // 49
        float* cl = smem + 2450;     // 49
        float* at = smem + 2499;     // 49
        float* wc = smem + 2548;     // 49
        float* af = smem + 2597;     // 49
        const float* fp = frames + ((size_t)(b * Fh + f)) * (Ph * Ah);
        for (int i = tid; i < Ph * Ah; i += 256) fr[i] = fp[i];
        if (tid < Ah) {
            cl[tid] = lang_cls[b * Ah + tid];
            float s = 0.f;
            for (int k = 0; k < Ah; ++k) s += lang_cls[b * Ah + k] * W_in[tid * Ah + k];
            tg[tid] = s;
        }
        __syncthreads();
        if (tid < Ph) {
            float s = 0.f;
            for (int a = 0; a < Ah; ++a) s += fr[tid * Ah + a] * tg[a];
            at[tid] = s;
        }
        __syncthreads();
        if (tid < 64) {
            float raw = (tid < Ph) ? at[tid] : -3.4e38f;
            float v = raw;
            for (int m = 32; m; m >>= 1) v = fmaxf(v, __shfl_xor(v, m));
            float e = (tid < Ph) ? expf(raw - v) : 0.f;
            float s = e;
            for (int m = 32; m; m >>= 1) s += __shfl_xor(s, m);
            if (tid < Ph) at[tid] = e / s;
        }
        __syncthreads();
        if (tid < Ah) {
            float s = 0.f;
            for (int p = 0; p < Ph; ++p) s += at[p] * fr[p * Ah + tid];
            wc[tid] = s;
        }
        __syncthreads();
        if (tid < Ah) {
            float s = 0.f;
            for (int a = 0; a < Ah; ++a)
                s += wc[a] * W_out[tid * (2 * Ah) + a] + cl[a] * W_out[tid * (2 * Ah) + Ah + a];
            af[tid] = tanhf(s);
        }
        __syncthreads();
        for (int d = tid; d < Dh; d += 256) {
            float s = b_fc2[d];
            for (int j = 0; j < Ah; ++j) s += af[j] * Wf2T[j * Dh + d];
            out[((size_t)(b * (Fh + Ch) + f)) * Dh + d] = s;
        }
    }
}

// ---------------- text -> fragment-major bf16 hi/lo (for k_w's B operand) ----------------
__global__ __launch_bounds__(256) void k_tfrag(const float* __restrict__ text,
                                               uint4* __restrict__ textH,
                                               uint4* __restrict__ textL) {
    int gid = blockIdx.x * 256 + threadIdx.x;  // 192*256 = 49152 exact
    int l  = gid & 63;
    int ct = (gid >> 6) & 3;
    int bk = gid >> 8;             // b*24 + ks
    int b  = bk / 24, ks = bk % 24;
    const float* src = text + ((size_t)(b * Lh + ct * 16 + (l & 15))) * Dh
                     + ks * 32 + (l >> 4) * 8;
    float4 p = *(const float4*)src;
    float4 q = *(const float4*)(src + 4);
    U h, lo;
    cvt2(p.x, p.y, h.u.x, lo.u.x);
    cvt2(p.z, p.w, h.u.y, lo.u.y);
    cvt2(q.x, q.y, h.u.z, lo.u.z);
    cvt2(q.z, q.w, h.u.w, lo.u.w);
    textH[gid] = h.u;
    textL[gid] = lo.u;
}

// ---------------- w[b,n]: A via dbuf LDS (XOR swizzle), B pre-converted from L2 ----------
// (R10 barriered version — measured best)
__global__ __launch_bounds__(256) void k_w(const float* __restrict__ grid,
                                           const uint4* __restrict__ textH,
                                           const uint4* __restrict__ textL,
                                           const int* __restrict__ gi,
                                           float* __restrict__ w,
                                           unsigned* __restrict__ m_u) {
    __shared__ float lds[2][4096];
    __shared__ unsigned mu[Ch];
    int b = blockIdx.y;
    int tid = threadIdx.x;
    int wv = tid >> 6, l = tid & 63;
    int n0 = blockIdx.x * 128;
    if (tid < Ch) mu[tid] = 0u;

    const float* gb = grid + (size_t)b * Nh * Dh;
    const uint4* pbh = textH + (size_t)b * 6144 + l;
    const uint4* pbl = textL + (size_t)b * 6144 + l;

    const float* srcA[4]; int dA[4];
#pragma unroll
    for (int r = 0; r < 4; ++r) {
        int s = r * 256 + tid, row = s >> 3, pos = s & 7;
        int rowg = n0 + row; if (rowg >= Nh) rowg = Nh - 1;
        srcA[r] = gb + (size_t)rowg * Dh + pos * 4;
        dA[r] = row * 32 + ((pos ^ (row & 7)) << 2);
    }
    int lm = l & 15, lh = l >> 4, r7 = lm & 7;
    int oA[2][2];
#pragma unroll
    for (int rt = 0; rt < 2; ++rt)
#pragma unroll
        for (int j = 0; j < 2; ++j)
            oA[rt][j] = (wv * 32 + rt * 16 + lm) * 32 + (((lh * 2 + j) ^ r7) << 2);

    {
        float4 v0 = *(const float4*)srcA[0];
        float4 v1 = *(const float4*)srcA[1];
        float4 v2 = *(const float4*)srcA[2];
        float4 v3 = *(const float4*)srcA[3];
        *(float4*)&lds[0][dA[0]] = v0;
        *(float4*)&lds[0][dA[1]] = v1;
        *(float4*)&lds[0][dA[2]] = v2;
        *(float4*)&lds[0][dA[3]] = v3;
    }
    __syncthreads();

    f32x4 acc[2][4];
#pragma unroll
    for (int i = 0; i < 2; ++i)
#pragma unroll
        for (int j = 0; j < 4; ++j) acc[i][j] = (f32x4){0.f, 0.f, 0.f, 0.f};

    for (int t = 0; t < 24; ++t) {
        int cur = t & 1;
        float4 p0, p1, p2, p3;
        bool pf = (t < 23);
        if (pf) {
            int o = (t + 1) * 32;
            p0 = *(const float4*)(srcA[0] + o);
            p1 = *(const float4*)(srcA[1] + o);
            p2 = *(const float4*)(srcA[2] + o);
            p3 = *(const float4*)(srcA[3] + o);
        }
        uint4 bh0 = pbh[t * 256 +   0], bh1 = pbh[t * 256 +  64];
        uint4 bh2 = pbh[t * 256 + 128], bh3 = pbh[t * 256 + 192];
        uint4 bl0 = pbl[t * 256 +   0], bl1 = pbl[t * 256 +  64];
        uint4 bl2 = pbl[t * 256 + 128], bl3 = pbl[t * 256 + 192];

        const float* L = lds[cur];
        float4 a00 = *(const float4*)&L[oA[0][0]];
        float4 a01 = *(const float4*)&L[oA[0][1]];
        float4 a10 = *(const float4*)&L[oA[1][0]];
        float4 a11 = *(const float4*)&L[oA[1][1]];
        bf16x8 ah0, al0, ah1, al1;
        cvt8(a00, a01, ah0, al0);
        cvt8(a10, a11, ah1, al1);

        uint4 bhu[4] = {bh0, bh1, bh2, bh3};
        uint4 blu[4] = {bl0, bl1, bl2, bl3};
#pragma unroll
        for (int ct = 0; ct < 4; ++ct) {
            U ubh, ubl; ubh.u = bhu[ct]; ubl.u = blu[ct];
            bf16x8 bh = ubh.v, bl = ubl.v;
            acc[0][ct] = __builtin_amdgcn_mfma_f32_16x16x32_bf16(ah0, bh, acc[0][ct], 0, 0, 0);
            acc[0][ct] = __builtin_amdgcn_mfma_f32_16x16x32_bf16(al0, bh, acc[0][ct], 0, 0, 0);
            acc[0][ct] = __builtin_amdgcn_mfma_f32_16x16x32_bf16(ah0, bl, acc[0][ct], 0, 0, 0);
            acc[1][ct] = __builtin_amdgcn_mfma_f32_16x16x32_bf16(ah1, bh, acc[1][ct], 0, 0, 0);
            acc[1][ct] = __builtin_amdgcn_mfma_f32_16x16x32_bf16(al1, bh, acc[1][ct], 0, 0, 0);
            acc[1][ct] = __builtin_amdgcn_mfma_f32_16x16x32_bf16(ah1, bl, acc[1][ct], 0, 0, 0);
        }
        if (pf) {
            float* D = lds[cur ^ 1];
            *(float4*)&D[dA[0]] = p0;
            *(float4*)&D[dA[1]] = p1;
            *(float4*)&D[dA[2]] = p2;
            *(float4*)&D[dA[3]] = p3;
        }
        __syncthreads();
    }

#pragma unroll
    for (int rt = 0; rt < 2; ++rt) {
        float m[4];
#pragma unroll
        for (int r = 0; r < 4; ++r) {
            m[r] = fmaxf(fmaxf(acc[rt][0][r], acc[rt][1][r]),
                         fmaxf(acc[rt][2][r], acc[rt][3][r]));
            m[r] = fmaxf(m[r], __shfl_xor(m[r], 1));
            m[r] = fmaxf(m[r], __shfl_xor(m[r], 2));
            m[r] = fmaxf(m[r], __shfl_xor(m[r], 4));
            m[r] = fmaxf(m[r], __shfl_xor(m[r], 8));
        }
        if (lm == 0) {
#pragma unroll
            for (int r = 0; r < 4; ++r) {
                int row = n0 + wv * 32 + rt * 16 + lh * 4 + r;
                if (row < Nh) {
                    w[b * Nh + row] = m[r];
                    unsigned u = __float_as_uint(m[r]);
                    u = (u & 0x80000000u) ? ~u : (u | 0x80000000u);
                    atomicMax(&mu[gi[b * Nh + row]], u);
                }
            }
        }
    }
    __syncthreads();
    if (tid < Ch && mu[tid]) atomicMax(&m_u[b * Ch + tid], mu[tid]);
}

// ---------------- e = exp(w - m): den-accumulate + compaction ----------------
__global__ __launch_bounds__(256) void k_epc(const float* __restrict__ w,
                                             const int* __restrict__ gi,
                                             const unsigned* __restrict__ m_u,
                                             float* __restrict__ den,
                                             int* __restrict__ cnt,
                                             int* __restrict__ bn,
                                             float* __restrict__ bp) {
    int b = blockIdx.y;
    int n = blockIdx.x * 256 + threadIdx.x;
    __shared__ float dn[Ch];
    if (threadIdx.x < Ch) dn[threadIdx.x] = 0.f;
    __syncthreads();
    if (n < Nh) {
        int c = gi[b * Nh + n];
        float e = expf(w[b * Nh + n] - dec_max(m_u[b * Ch + c]));
        atomicAdd(&dn[c], e);
        if (e > CUTE) {
            int pos = atomicAdd(&cnt[b * Ch + c], 1);
            if (pos < CAP) {
                bn[(b * Ch + c) * CAP + pos] = n;
                bp[(b * Ch + c) * CAP + pos] = e;
            }
        }
    }
    __syncthreads();
    if (threadIdx.x < Ch && dn[threadIdx.x] != 0.f)
        atomicAdd(&den[b * Ch + threadIdx.x], dn[threadIdx.x]);
}

// ---------------- chunked segment weighted sums -> Spart[b][c][ch][d] ----------------
__global__ __launch_bounds__(256) void k_S3(const float* __restrict__ grid,
                                            const int* __restrict__ cnt,
                                            const int* __restrict__ bn,
                                            const float* __restrict__ bp,
                                            float* __restrict__ Spart) {
    int c = blockIdx.x, dq = blockIdx.y;
    int b = blockIdx.z >> 3, ch = blockIdx.z & 7;
    int d = dq * 256 + threadIdx.x;
    int len = cnt[b * Ch + c]; if (len > CAP) len = CAP;
    int i0 = ch * (CAP / NCH);
    int i1 = i0 + (CAP / NCH); if (i1 > len) i1 = len;
    size_t base = (size_t)(b * Ch + c) * CAP;
    size_t po = ((size_t)(b * Ch + c) * NCH + ch) * Dh + d;
    const float* gb = grid + (size_t)b * Nh * Dh + d;
    float a[8] = {0.f, 0.f, 0.f, 0.f, 0.f, 0.f, 0.f, 0.f};
    int i = i0;
    for (; i + 8 <= i1; i += 8) {
        int nn[8]; float pp[8];
#pragma unroll
        for (int j = 0; j < 8; ++j) { nn[j] = bn[base + i + j]; pp[j] = bp[base + i + j]; }
#pragma unroll
        for (int j = 0; j < 8; ++j) a[j] += pp[j] * gb[(size_t)nn[j] * Dh];
    }
    for (; i < i1; ++i) a[0] += bp[base + i] * gb[(size_t)bn[base + i] * Dh];
    Spart[po] = ((a[0] + a[1]) + (a[2] + a[3])) + ((a[4] + a[5]) + (a[6] + a[7]));
}

// ---- gg2f: inline Spart-reduce + (S/den)@W_grid.T + b_grid + LN-combine epilogue ----
__global__ __launch_bounds__(256) void k_gg2(const float* __restrict__ Spart,
                                             const float* __restrict__ den,
                                             const uint4* __restrict__ WgH,
                                             const uint4* __restrict__ WgL,
                                             const float* __restrict__ bg,
                                             const float* __restrict__ cn,
                                             const float* __restrict__ lang,
                                             float* __restrict__ out) {
    __shared__ float lds[2][4096];
    int tid = threadIdx.x;
    int wv = tid >> 6, l = tid & 63;
    int m0 = blockIdx.y * 128;
    int dt = blockIdx.x;

    const uint4* pbh = WgH + (size_t)dt * 256 + l;
    const uint4* pbl = WgL + (size_t)dt * 256 + l;

    int rowgA[4], posA[4], dA[4];
#pragma unroll
    for (int r = 0; r < 4; ++r) {
        int s = r * 256 + tid, row = s >> 3, pos = s & 7;
        int rowg = m0 + row; if (rowg >= Bh * Ch) rowg = Bh * Ch - 1;
        rowgA[r] = rowg; posA[r] = pos * 4;
        dA[r] = row * 32 + ((pos ^ (row & 7)) << 2);
    }
    int lm = l & 15, lh = l >> 4, r7 = lm & 7;
    int oA[2][2];
#pragma unroll
    for (int rt = 0; rt < 2; ++rt)
#pragma unroll
        for (int j = 0; j < 2; ++j)
            oA[rt][j] = (wv * 32 + rt * 16 + lm) * 32 + (((lh * 2 + j) ^ r7) << 2);

    {
        float4 v0 = sumS(Spart, rowgA[0], posA[0]);
        float4 v1 = sumS(Spart, rowgA[1], posA[1]);
        float4 v2 = sumS(Spart, rowgA[2], posA[2]);
        float4 v3 = sumS(Spart, rowgA[3], posA[3]);
        *(float4*)&lds[0][dA[0]] = v0;
        *(float4*)&lds[0][dA[1]] = v1;
        *(float4*)&lds[0][dA[2]] = v2;
        *(float4*)&lds[0][dA[3]] = v3;
    }
    __syncthreads();

    f32x4 acc[2][4];
#pragma unroll
    for (int i = 0; i < 2; ++i)
#pragma unroll
        for (int j = 0; j < 4; ++j) acc[i][j] = (f32x4){0.f, 0.f, 0.f, 0.f};

    for (int t = 0; t < 24; ++t) {
        int cur = t & 1;
        float4 p0, p1, p2, p3;
        bool pf = (t < 23);
        if (pf) {
            int o = (t + 1) * 32;
            p0 = sumS(Spart, rowgA[0], posA[0] + o);
            p1 = sumS(Spart, rowgA[1], posA[1] + o);
            p2 = sumS(Spart, rowgA[2], posA[2] + o);
            p3 = sumS(Spart, rowgA[3], posA[3] + o);
        }
        uint4 bh0 = pbh[t * 3072 +   0], bh1 = pbh[t * 3072 +  64];
        uint4 bh2 = pbh[t * 3072 + 128], bh3 = pbh[t * 3072 + 192];
        uint4 bl0 = pbl[t * 3072 +   0], bl1 = pbl[t * 3072 +  64];
        uint4 bl2 = pbl[t * 3072 + 128], bl3 = pbl[t * 3072 + 192];

        const float* L = lds[cur];
        float4 a00 = *(const float4*)&L[oA[0][0]];
        float4 a01 = *(const float4*)&L[oA[0][1]];
        float4 a10 = *(const float4*)&L[oA[1][0]];
        float4 a11 = *(const float4*)&L[oA[1][1]];
        bf16x8 ah0, al0, ah1, al1;
        cvt8(a00, a01, ah0, al0);
        cvt8(a10, a11, ah1, al1);

        uint4 bhu[4] = {bh0, bh1, bh2, bh3};
        uint4 blu[4] = {bl0, bl1, bl2, bl3};
#pragma unroll
        for (int ct = 0; ct < 4; ++ct) {
            U ubh, ubl; ubh.u = bhu[ct]; ubl.u = blu[ct];
            bf16x8 bh = ubh.v, bl = ubl.v;
            acc[0][ct] = __builtin_amdgcn_mfma_f32_16x16x32_bf16(ah0, bh, acc[0][ct], 0, 0, 0);
            acc[0][ct] = __builtin_amdgcn_mfma_f32_16x16x32_bf16(al0, bh, acc[0][ct], 0, 0, 0);
            acc[0][ct] = __builtin_amdgcn_mfma_f32_16x16x32_bf16(ah0, bl, acc[0][ct], 0, 0, 0);
            acc[1][ct] = __builtin_amdgcn_mfma_f32_16x16x32_bf16(ah1, bh, acc[1][ct], 0, 0, 0);
            acc[1][ct] = __builtin_amdgcn_mfma_f32_16x16x32_bf16(al1, bh, acc[1][ct], 0, 0, 0);
            acc[1][ct] = __builtin_amdgcn_mfma_f32_16x16x32_bf16(ah1, bl, acc[1][ct], 0, 0, 0);
        }
        if (pf) {
            float* D = lds[cur ^ 1];
            *(float4*)&D[dA[0]] = p0;
            *(float4*)&D[dA[1]] = p1;
            *(float4*)&D[dA[2]] = p2;
            *(float4*)&D[dA[3]] = p3;
        }
        __syncthreads();
    }

    // fused epilogue: out[b][50+c][d] = cn*lang[b,0,d] + (den>0 ? acc/den + bg[d] : 0)
#pragma unroll
    for (int rt = 0; rt < 2; ++rt) {
#pragma unroll
        for (int r = 0; r < 4; ++r) {
            int row = m0 + wv * 32 + rt * 16 + lh * 4 + r;
            if (row < Bh * Ch) {
                float dv = den[row];
                float inv = (dv > 0.f) ? 1.f / dv : 0.f;
                int bb = row / Ch, cc = row - bb * Ch;
                const float* lrow = lang + (size_t)bb * Lh * Dh;
#pragma unroll
                for (int ct = 0; ct < 4; ++ct) {
                    int d = dt * 64 + ct * 16 + lm;
                    float gm = (dv > 0.f) ? acc[rt][ct][r] * inv + bg[d] : 0.f;
                    out[((size_t)(bb * (Fh + Ch) + Fh + cc)) * Dh + d] =
                        cn[(size_t)row * Dh + d] * lrow[d] + gm;
                }
            }
        }
    }
}

extern "C" void kernel_launch(void* const* d_in, const int* in_sizes, int n_in,
                              void* d_out, int out_size, void* d_ws, size_t ws_size,
                              hipStream_t stream) {
    (void)in_sizes; (void)n_in; (void)out_size; (void)ws_size;
    const float* lang      = (const float*)d_in[0];
    const float* lang_cls  = (const float*)d_in[1];
    const float* frames    = (const float*)d_in[2];
    const float* cands     = (const float*)d_in[3];
    const float* grid_fts  = (const float*)d_in[4];
    const int*   grid_idx  = (const int*)d_in[5];
    const float* W_in      = (const float*)d_in[6];
    const float* W_out     = (const float*)d_in[7];
    const float* W_fc2     = (const float*)d_in[8];
    const float* b_fc2     = (const float*)d_in[9];
    const float* W_text    = (const float*)d_in[10];
    const float* b_text    = (const float*)d_in[11];
    const float* W_grid    = (const float*)d_in[12];
    const float* b_grid    = (const float*)d_in[13];
    const float* W_cand    = (const float*)d_in[14];
    const float* b_cand    = (const float*)d_in[15];
    const float* ln_g      = (const float*)d_in[16];
    const float* ln_b      = (const float*)d_in[17];
    float* out = (float*)d_out;
    float* ws  = (float*)d_ws;

    float*    wbuf  = ws;                        // 160000
    unsigned* m_u   = (unsigned*)(ws + 160000);  // 288
    float*    den   = ws + 160288;               // 288
    int*      cnt   = (int*)(ws + 160576);       // 288
    int*      bn    = (int*)(ws + 160864);       // 589824
    float*    bp    = ws + 750688;               // 589824
    float*    Spart = ws + 1340512;              // 1769472
    float*    cn    = ws + 3109984;              // 221184
    uint4*    textH = (uint4*)(ws + 3331168);    // 196608 floats
    uint4*    textL = (uint4*)(ws + 3527776);    // 196608 floats
    uint4*    WgH   = (uint4*)(ws + 3945568);    // 294912 floats
    uint4*    WgL   = (uint4*)(ws + 4240480);    // 294912 floats
    uint4*    WtH   = (uint4*)(ws + 4535392);    // 294912 floats
    uint4*    WtL   = (uint4*)(ws + 4830304);    // 294912 floats
    float*    Wf2T  = ws + 5125216;              // 37632
    float*    text  = ws + 5162848;              // 393216

    hipLaunchKernelGGL(k_prep,   dim3(1012), dim3(256), 0, stream,
                       W_grid, W_text, W_fc2, cands, W_cand, b_cand, ln_g, ln_b,
                       WgH, WgL, WtH, WtL, Wf2T, cn, m_u, den, cnt);
    hipLaunchKernelGGL(k_tf,     dim3(448), dim3(256), 0, stream,
                       lang, WtH, WtL, b_text, frames, lang_cls, W_in, W_out, Wf2T, b_fc2,
                       text, out);
    hipLaunchKernelGGL(k_tfrag,  dim3(192), dim3(256), 0, stream, text, textH, textL);
    hipLaunchKernelGGL(k_w,      dim3((Nh + 127) / 128, Bh), dim3(256), 0, stream,
                       grid_fts, textH, textL, grid_idx, wbuf, m_u);
    hipLaunchKernelGGL(k_epc,    dim3(79, Bh), dim3(256), 0, stream,
                       wbuf, grid_idx, m_u, den, cnt, bn, bp);
    hipLaunchKernelGGL(k_S3,     dim3(Ch, 3, Bh * NCH), dim3(256), 0, stream,
                       grid_fts, cnt, bn, bp, Spart);
    hipLaunchKernelGGL(k_gg2,    dim3(12, 3), dim3(256), 0, stream,
                       Spart, den, WgH, WgL, b_grid, cn, lang, out);
}

// Round 15
// 241.692 us; speedup vs baseline: 1.3620x; 1.3620x over previous
//
#include <hip/hip_runtime.h>
#include <math.h>

#define Bh 8
#define Lh 64
#define Dh 768
#define Fh 50
#define Ph 49
#define Ah 49
#define Nh 20000
#define Ch 36
#define CAP 2048
#define NCH 8
#define CUTE 2e-6f

typedef __bf16 bf16x8 __attribute__((ext_vector_type(8)));
typedef float f32x4 __attribute__((ext_vector_type(4)));
union U { uint4 u; bf16x8 v; };

__device__ __forceinline__ void cvt2(float a0, float a1, unsigned& h, unsigned& l) {
    unsigned u0 = __float_as_uint(a0), u1 = __float_as_uint(a1);
    unsigned h0 = u0 & 0xFFFF0000u, h1 = u1 & 0xFFFF0000u;
    h = (h0 >> 16) | h1;
    float l0 = a0 - __uint_as_float(h0);
    float l1 = a1 - __uint_as_float(h1);
    l = (__float_as_uint(l0) >> 16) | (__float_as_uint(l1) & 0xFFFF0000u);
}

__device__ __forceinline__ void cvt8(float4 p, float4 q, bf16x8& h8, bf16x8& l8) {
    U h, l;
    cvt2(p.x, p.y, h.u.x, l.u.x);
    cvt2(p.z, p.w, h.u.y, l.u.y);
    cvt2(q.x, q.y, h.u.z, l.u.z);
    cvt2(q.z, q.w, h.u.w, l.u.w);
    h8 = h.v; l8 = l.v;
}

__device__ __forceinline__ float dec_max(unsigned u) {
    if (u == 0u) return 0.f;
    return (u & 0x80000000u) ? __uint_as_float(u ^ 0x80000000u) : __uint_as_float(~u);
}

// ---- prep: [0,576) W frags | [576,723) Wf2T | 723 zero | [724,1012) candidate LN ----
__global__ __launch_bounds__(256) void k_prep(const float* __restrict__ Wg,
                                              const float* __restrict__ Wt,
                                              const float* __restrict__ Wf2,
                                              const float* __restrict__ cands,
                                              const float* __restrict__ W_cand,
                                              const float* __restrict__ b_cand,
                                              const float* __restrict__ ln_g,
                                              const float* __restrict__ ln_b,
                                              uint4* __restrict__ WgH, uint4* __restrict__ WgL,
                                              uint4* __restrict__ WtH, uint4* __restrict__ WtL,
                                              float* __restrict__ Wf2T,
                                              float* __restrict__ cn,
                                              unsigned* __restrict__ m_u,
                                              float* __restrict__ den,
                                              int* __restrict__ cnt) {
    __shared__ float cv[Dh];
    __shared__ float red[8];
    __shared__ float mu_s, rs_s;
    int bx = blockIdx.x, tid = threadIdx.x;
    if (bx < 576) {
        bool g = bx < 288;
        int gid = (g ? bx : bx - 288) * 256 + tid;   // < 73728
        const float* W = g ? Wg : Wt;
        int l = gid & 63;
        int rest = gid >> 6;
        int ct = rest % 48, ks = rest / 48;
        const float* src = W + (size_t)(ct * 16 + (l & 15)) * Dh + ks * 32 + (l >> 4) * 8;
        float4 p = *(const float4*)src;
        float4 q = *(const float4*)(src + 4);
        U h, lo;
        cvt2(p.x, p.y, h.u.x, lo.u.x);
        cvt2(p.z, p.w, h.u.y, lo.u.y);
        cvt2(q.x, q.y, h.u.z, lo.u.z);
        cvt2(q.z, q.w, h.u.w, lo.u.w);
        if (g) { WgH[gid] = h.u; WgL[gid] = lo.u; }
        else   { WtH[gid] = h.u; WtL[gid] = lo.u; }
    } else if (bx < 723) {
        int i = (bx - 576) * 256 + tid;              // < 37632 = 768*49 exact
        int d = i / 49, j = i - d * 49;
        Wf2T[j * Dh + d] = Wf2[i];
    } else if (bx == 723) {
        for (int i = tid; i < Bh * Ch; i += 256) { m_u[i] = 0u; den[i] = 0.f; cnt[i] = 0; }
    } else {
        // candidate encoder LN -> cn[b*Ch+c][d]
        int idx = bx - 724;               // [0,288)
        int b = idx / Ch, c = idx % Ch;
        float cx = cands[(b * Ch + c) * 2 + 0], cy = cands[(b * Ch + c) * 2 + 1];
        for (int d = tid; d < Dh; d += 256)
            cv[d] = W_cand[d * 2] * cx + W_cand[d * 2 + 1] * cy + b_cand[d];
        __syncthreads();
        float ls = 0.f;
        for (int d = tid; d < Dh; d += 256) ls += cv[d];
        for (int m = 32; m; m >>= 1) ls += __shfl_xor(ls, m);
        if ((tid & 63) == 0) red[tid >> 6] = ls;
        __syncthreads();
        if (tid == 0) mu_s = (red[0] + red[1] + red[2] + red[3]) * (1.f / Dh);
        __syncthreads();
        float mu = mu_s;
        float lv = 0.f;
        for (int d = tid; d < Dh; d += 256) { float t = cv[d] - mu; lv += t * t; }
        for (int m = 32; m; m >>= 1) lv += __shfl_xor(lv, m);
        if ((tid & 63) == 0) red[4 + (tid >> 6)] = lv;
        __syncthreads();
        if (tid == 0) rs_s = rsqrtf((red[4] + red[5] + red[6] + red[7]) * (1.f / Dh) + 1e-12f);
        __syncthreads();
        float rs = rs_s;
#pragma unroll
        for (int j = 0; j < 3; ++j) {
            int d = tid + j * 256;
            cn[(size_t)(b * Ch + c) * Dh + d] = (cv[d] - mu) * rs * ln_g[d] + ln_b[d];
        }
    }
}

// ---------------- tf: [0,48) text MFMA GEMM | [48,448) frames path ----------------
__global__ __launch_bounds__(256) void k_tf(const float* __restrict__ lang,
                                            const uint4* __restrict__ WtH,
                                            const uint4* __restrict__ WtL,
                                            const float* __restrict__ bt,
                                            const float* __restrict__ frames,
                                            const float* __restrict__ lang_cls,
                                            const float* __restrict__ W_in,
                                            const float* __restrict__ W_out,
                                            const float* __restrict__ Wf2T,
                                            const float* __restrict__ b_fc2,
                                            float* __restrict__ text,
                                            float* __restrict__ out) {
    __shared__ float smem[8192];
    int bx = blockIdx.x;
    int tid = threadIdx.x;

    if (bx < 48) {
        float (*lds)[4096] = (float(*)[4096])smem;
        int wv = tid >> 6, l = tid & 63;
        int dt = bx % 12;
        int m0 = (bx / 12) * 128;

        const uint4* pbh = WtH + (size_t)dt * 256 + l;
        const uint4* pbl = WtL + (size_t)dt * 256 + l;

        const float* srcA[4]; int dA[4];
#pragma unroll
        for (int r = 0; r < 4; ++r) {
            int s = r * 256 + tid, row = s >> 3, pos = s & 7;
            srcA[r] = lang + (size_t)(m0 + row) * Dh + pos * 4;
            dA[r] = row * 32 + ((pos ^ (row & 7)) << 2);
        }
        int lm = l & 15, lh = l >> 4, r7 = lm & 7;
        int oA[2][2];
#pragma unroll
        for (int rt = 0; rt < 2; ++rt)
#pragma unroll
            for (int j = 0; j < 2; ++j)
                oA[rt][j] = (wv * 32 + rt * 16 + lm) * 32 + (((lh * 2 + j) ^ r7) << 2);

        {
            float4 v0 = *(const float4*)srcA[0];
            float4 v1 = *(const float4*)srcA[1];
            float4 v2 = *(const float4*)srcA[2];
            float4 v3 = *(const float4*)srcA[3];
            *(float4*)&lds[0][dA[0]] = v0;
            *(float4*)&lds[0][dA[1]] = v1;
            *(float4*)&lds[0][dA[2]] = v2;
            *(float4*)&lds[0][dA[3]] = v3;
        }
        __syncthreads();

        f32x4 acc[2][4];
#pragma unroll
        for (int i = 0; i < 2; ++i)
#pragma unroll
            for (int j = 0; j < 4; ++j) acc[i][j] = (f32x4){0.f, 0.f, 0.f, 0.f};

        for (int t = 0; t < 24; ++t) {
            int cur = t & 1;
            float4 p0, p1, p2, p3;
            bool pf = (t < 23);
            if (pf) {
                int o = (t + 1) * 32;
                p0 = *(const float4*)(srcA[0] + o);
                p1 = *(const float4*)(srcA[1] + o);
                p2 = *(const float4*)(srcA[2] + o);
                p3 = *(const float4*)(srcA[3] + o);
            }
            uint4 bh0 = pbh[t * 3072 +   0], bh1 = pbh[t * 3072 +  64];
            uint4 bh2 = pbh[t * 3072 + 128], bh3 = pbh[t * 3072 + 192];
            uint4 bl0 = pbl[t * 3072 +   0], bl1 = pbl[t * 3072 +  64];
            uint4 bl2 = pbl[t * 3072 + 128], bl3 = pbl[t * 3072 + 192];

            const float* L = lds[cur];
            float4 a00 = *(const float4*)&L[oA[0][0]];
            float4 a01 = *(const float4*)&L[oA[0][1]];
            float4 a10 = *(const float4*)&L[oA[1][0]];
            float4 a11 = *(const float4*)&L[oA[1][1]];
            bf16x8 ah0, al0, ah1, al1;
            cvt8(a00, a01, ah0, al0);
            cvt8(a10, a11, ah1, al1);

            uint4 bhu[4] = {bh0, bh1, bh2, bh3};
            uint4 blu[4] = {bl0, bl1, bl2, bl3};
#pragma unroll
            for (int ct = 0; ct < 4; ++ct) {
                U ubh, ubl; ubh.u = bhu[ct]; ubl.u = blu[ct];
                bf16x8 bh = ubh.v, bl = ubl.v;
                acc[0][ct] = __builtin_amdgcn_mfma_f32_16x16x32_bf16(ah0, bh, acc[0][ct], 0, 0, 0);
                acc[0][ct] = __builtin_amdgcn_mfma_f32_16x16x32_bf16(al0, bh, acc[0][ct], 0, 0, 0);
                acc[0][ct] = __builtin_amdgcn_mfma_f32_16x16x32_bf16(ah0, bl, acc[0][ct], 0, 0, 0);
                acc[1][ct] = __builtin_amdgcn_mfma_f32_16x16x32_bf16(ah1, bh, acc[1][ct], 0, 0, 0);
                acc[1][ct] = __builtin_amdgcn_mfma_f32_16x16x32_bf16(al1, bh, acc[1][ct], 0, 0, 0);
                acc[1][ct] = __builtin_amdgcn_mfma_f32_16x16x32_bf16(ah1, bl, acc[1][ct], 0, 0, 0);
            }
            if (pf) {
                float* D = lds[cur ^ 1];
                *(float4*)&D[dA[0]] = p0;
                *(float4*)&D[dA[1]] = p1;
                *(float4*)&D[dA[2]] = p2;
                *(float4*)&D[dA[3]] = p3;
            }
            __syncthreads();
        }

#pragma unroll
        for (int rt = 0; rt < 2; ++rt) {
#pragma unroll
            for (int r = 0; r < 4; ++r) {
                int row = m0 + wv * 32 + rt * 16 + lh * 4 + r;
#pragma unroll
                for (int ct = 0; ct < 4; ++ct) {
                    int d = dt * 64 + ct * 16 + lm;
                    text[(size_t)row * Dh + d] = acc[rt][ct][r] + bt[d];
                }
            }
        }
    } else {
        int fid = bx - 48;
        int b = fid / Fh, f = fid % Fh;
        float* fr = smem;            // 2401
        float* tg = smem + 2401;     // 49
        float* cl = smem + 2450;     // 49
        float* at = smem + 2499;     // 49
        float* wc = smem + 2548;     // 49
        float* af = smem + 2597;     // 49
        const float* fp = frames + ((size_t)(b * Fh + f)) * (Ph * Ah);
        for (int i = tid; i < Ph * Ah; i += 256) fr[i] = fp[i];
        if (tid < Ah) {
            cl[tid] = lang_cls[b * Ah + tid];
            float s = 0.f;
            for (int k = 0; k < Ah; ++k) s += lang_cls[b * Ah + k] * W_in[tid * Ah + k];
            tg[tid] = s;
        }
        __syncthreads();
        if (tid < Ph) {
            float s = 0.f;
            for (int a = 0; a < Ah; ++a) s += fr[tid * Ah + a] * tg[a];
            at[tid] = s;
        }
        __syncthreads();
        if (tid < 64) {
            float raw = (tid < Ph) ? at[tid] : -3.4e38f;
            float v = raw;
            for (int m = 32; m; m >>= 1) v = fmaxf(v, __shfl_xor(v, m));
            float e = (tid < Ph) ? expf(raw - v) : 0.f;
            float s = e;
            for (int m = 32; m; m >>= 1) s += __shfl_xor(s, m);
            if (tid < Ph) at[tid] = e / s;
        }
        __syncthreads();
        if (tid < Ah) {
            float s = 0.f;
            for (int p = 0; p < Ph; ++p) s += at[p] * fr[p * Ah + tid];
            wc[tid] = s;
        }
        __syncthreads();
        if (tid < Ah) {
            float s = 0.f;
            for (int a = 0; a < Ah; ++a)
                s += wc[a] * W_out[tid * (2 * Ah) + a] + cl[a] * W_out[tid * (2 * Ah) + Ah + a];
            af[tid] = tanhf(s);
        }
        __syncthreads();
        for (int d = tid; d < Dh; d += 256) {
            float s = b_fc2[d];
            for (int j = 0; j < Ah; ++j) s += af[j] * Wf2T[j * Dh + d];
            out[((size_t)(b * (Fh + Ch) + f)) * Dh + d] = s;
        }
    }
}

// ---------------- text -> fragment-major bf16 hi/lo (for k_w's B operand) ----------------
__global__ __launch_bounds__(256) void k_tfrag(const float* __restrict__ text,
                                               uint4* __restrict__ textH,
                                               uint4* __restrict__ textL) {
    int gid = blockIdx.x * 256 + threadIdx.x;  // 192*256 = 49152 exact
    int l  = gid & 63;
    int ct = (gid >> 6) & 3;
    int bk = gid >> 8;             // b*24 + ks
    int b  = bk / 24, ks = bk % 24;
    const float* src = text + ((size_t)(b * Lh + ct * 16 + (l & 15))) * Dh
                     + ks * 32 + (l >> 4) * 8;
    float4 p = *(const float4*)src;
    float4 q = *(const float4*)(src + 4);
    U h, lo;
    cvt2(p.x, p.y, h.u.x, lo.u.x);
    cvt2(p.z, p.w, h.u.y, lo.u.y);
    cvt2(q.x, q.y, h.u.z, lo.u.z);
    cvt2(q.z, q.w, h.u.w, lo.u.w);
    textH[gid] = h.u;
    textL[gid] = lo.u;
}

// ---------------- w[b,n]: A via dbuf LDS (XOR swizzle), B pre-converted from L2 ----------
__global__ __launch_bounds__(256) void k_w(const float* __restrict__ grid,
                                           const uint4* __restrict__ textH,
                                           const uint4* __restrict__ textL,
                                           const int* __restrict__ gi,
                                           float* __restrict__ w,
                                           unsigned* __restrict__ m_u) {
    __shared__ float lds[2][4096];
    __shared__ unsigned mu[Ch];
    int b = blockIdx.y;
    int tid = threadIdx.x;
    int wv = tid >> 6, l = tid & 63;
    int n0 = blockIdx.x * 128;
    if (tid < Ch) mu[tid] = 0u;

    const float* gb = grid + (size_t)b * Nh * Dh;
    const uint4* pbh = textH + (size_t)b * 6144 + l;
    const uint4* pbl = textL + (size_t)b * 6144 + l;

    const float* srcA[4]; int dA[4];
#pragma unroll
    for (int r = 0; r < 4; ++r) {
        int s = r * 256 + tid, row = s >> 3, pos = s & 7;
        int rowg = n0 + row; if (rowg >= Nh) rowg = Nh - 1;
        srcA[r] = gb + (size_t)rowg * Dh + pos * 4;
        dA[r] = row * 32 + ((pos ^ (row & 7)) << 2);
    }
    int lm = l & 15, lh = l >> 4, r7 = lm & 7;
    int oA[2][2];
#pragma unroll
    for (int rt = 0; rt < 2; ++rt)
#pragma unroll
        for (int j = 0; j < 2; ++j)
            oA[rt][j] = (wv * 32 + rt * 16 + lm) * 32 + (((lh * 2 + j) ^ r7) << 2);

    {
        float4 v0 = *(const float4*)srcA[0];
        float4 v1 = *(const float4*)srcA[1];
        float4 v2 = *(const float4*)srcA[2];
        float4 v3 = *(const float4*)srcA[3];
        *(float4*)&lds[0][dA[0]] = v0;
        *(float4*)&lds[0][dA[1]] = v1;
        *(float4*)&lds[0][dA[2]] = v2;
        *(float4*)&lds[0][dA[3]] = v3;
    }
    __syncthreads();

    f32x4 acc[2][4];
#pragma unroll
    for (int i = 0; i < 2; ++i)
#pragma unroll
        for (int j = 0; j < 4; ++j) acc[i][j] = (f32x4){0.f, 0.f, 0.f, 0.f};

    for (int t = 0; t < 24; ++t) {
        int cur = t & 1;
        float4 p0, p1, p2, p3;
        bool pf = (t < 23);
        if (pf) {
            int o = (t + 1) * 32;
            p0 = *(const float4*)(srcA[0] + o);
            p1 = *(const float4*)(srcA[1] + o);
            p2 = *(const float4*)(srcA[2] + o);
            p3 = *(const float4*)(srcA[3] + o);
        }
        uint4 bh0 = pbh[t * 256 +   0], bh1 = pbh[t * 256 +  64];
        uint4 bh2 = pbh[t * 256 + 128], bh3 = pbh[t * 256 + 192];
        uint4 bl0 = pbl[t * 256 +   0], bl1 = pbl[t * 256 +  64];
        uint4 bl2 = pbl[t * 256 + 128], bl3 = pbl[t * 256 + 192];

        const float* L = lds[cur];
        float4 a00 = *(const float4*)&L[oA[0][0]];
        float4 a01 = *(const float4*)&L[oA[0][1]];
        float4 a10 = *(const float4*)&L[oA[1][0]];
        float4 a11 = *(const float4*)&L[oA[1][1]];
        bf16x8 ah0, al0, ah1, al1;
        cvt8(a00, a01, ah0, al0);
        cvt8(a10, a11, ah1, al1);

        uint4 bhu[4] = {bh0, bh1, bh2, bh3};
        uint4 blu[4] = {bl0, bl1, bl2, bl3};
#pragma unroll
        for (int ct = 0; ct < 4; ++ct) {
            U ubh, ubl; ubh.u = bhu[ct]; ubl.u = blu[ct];
            bf16x8 bh = ubh.v, bl = ubl.v;
            acc[0][ct] = __builtin_amdgcn_mfma_f32_16x16x32_bf16(ah0, bh, acc[0][ct], 0, 0, 0);
            acc[0][ct] = __builtin_amdgcn_mfma_f32_16x16x32_bf16(al0, bh, acc[0][ct], 0, 0, 0);
            acc[0][ct] = __builtin_amdgcn_mfma_f32_16x16x32_bf16(ah0, bl, acc[0][ct], 0, 0, 0);
            acc[1][ct] = __builtin_amdgcn_mfma_f32_16x16x32_bf16(ah1, bh, acc[1][ct], 0, 0, 0);
            acc[1][ct] = __builtin_amdgcn_mfma_f32_16x16x32_bf16(al1, bh, acc[1][ct], 0, 0, 0);
            acc[1][ct] = __builtin_amdgcn_mfma_f32_16x16x32_bf16(ah1, bl, acc[1][ct], 0, 0, 0);
        }
        if (pf) {
            float* D = lds[cur ^ 1];
            *(float4*)&D[dA[0]] = p0;
            *(float4*)&D[dA[1]] = p1;
            *(float4*)&D[dA[2]] = p2;
            *(float4*)&D[dA[3]] = p3;
        }
        __syncthreads();
    }

#pragma unroll
    for (int rt = 0; rt < 2; ++rt) {
        float m[4];
#pragma unroll
        for (int r = 0; r < 4; ++r) {
            m[r] = fmaxf(fmaxf(acc[rt][0][r], acc[rt][1][r]),
                         fmaxf(acc[rt][2][r], acc[rt][3][r]));
            m[r] = fmaxf(m[r], __shfl_xor(m[r], 1));
            m[r] = fmaxf(m[r], __shfl_xor(m[r], 2));
            m[r] = fmaxf(m[r], __shfl_xor(m[r], 4));
            m[r] = fmaxf(m[r], __shfl_xor(m[r], 8));
        }
        if (lm == 0) {
#pragma unroll
            for (int r = 0; r < 4; ++r) {
                int row = n0 + wv * 32 + rt * 16 + lh * 4 + r;
                if (row < Nh) {
                    w[b * Nh + row] = m[r];
                    unsigned u = __float_as_uint(m[r]);
                    u = (u & 0x80000000u) ? ~u : (u | 0x80000000u);
                    atomicMax(&mu[gi[b * Nh + row]], u);
                }
            }
        }
    }
    __syncthreads();
    if (tid < Ch && mu[tid]) atomicMax(&m_u[b * Ch + tid], mu[tid]);
}

// ---------------- e = exp(w - m): den-accumulate + compaction ----------------
__global__ __launch_bounds__(256) void k_epc(const float* __restrict__ w,
                                             const int* __restrict__ gi,
                                             const unsigned* __restrict__ m_u,
                                             float* __restrict__ den,
                                             int* __restrict__ cnt,
                                             int* __restrict__ bn,
                                             float* __restrict__ bp) {
    int b = blockIdx.y;
    int n = blockIdx.x * 256 + threadIdx.x;
    __shared__ float dn[Ch];
    if (threadIdx.x < Ch) dn[threadIdx.x] = 0.f;
    __syncthreads();
    if (n < Nh) {
        int c = gi[b * Nh + n];
        float e = expf(w[b * Nh + n] - dec_max(m_u[b * Ch + c]));
        atomicAdd(&dn[c], e);
        if (e > CUTE) {
            int pos = atomicAdd(&cnt[b * Ch + c], 1);
            if (pos < CAP) {
                bn[(b * Ch + c) * CAP + pos] = n;
                bp[(b * Ch + c) * CAP + pos] = e;
            }
        }
    }
    __syncthreads();
    if (threadIdx.x < Ch && dn[threadIdx.x] != 0.f)
        atomicAdd(&den[b * Ch + threadIdx.x], dn[threadIdx.x]);
}

// ---------------- chunked segment weighted sums -> Spart[b][c][ch][d] ----------------
__global__ __launch_bounds__(256) void k_S3(const float* __restrict__ grid,
                                            const int* __restrict__ cnt,
                                            const int* __restrict__ bn,
                                            const float* __restrict__ bp,
                                            float* __restrict__ Spart) {
    int c = blockIdx.x, dq = blockIdx.y;
    int b = blockIdx.z >> 3, ch = blockIdx.z & 7;
    int d = dq * 256 + threadIdx.x;
    int len = cnt[b * Ch + c]; if (len > CAP) len = CAP;
    int i0 = ch * (CAP / NCH);
    int i1 = i0 + (CAP / NCH); if (i1 > len) i1 = len;
    size_t base = (size_t)(b * Ch + c) * CAP;
    size_t po = ((size_t)(b * Ch + c) * NCH + ch) * Dh + d;
    const float* gb = grid + (size_t)b * Nh * Dh + d;
    float a[8] = {0.f, 0.f, 0.f, 0.f, 0.f, 0.f, 0.f, 0.f};
    int i = i0;
    for (; i + 8 <= i1; i += 8) {
        int nn[8]; float pp[8];
#pragma unroll
        for (int j = 0; j < 8; ++j) { nn[j] = bn[base + i + j]; pp[j] = bp[base + i + j]; }
#pragma unroll
        for (int j = 0; j < 8; ++j) a[j] += pp[j] * gb[(size_t)nn[j] * Dh];
    }
    for (; i < i1; ++i) a[0] += bp[base + i] * gb[(size_t)bn[base + i] * Dh];
    Spart[po] = ((a[0] + a[1]) + (a[2] + a[3])) + ((a[4] + a[5]) + (a[6] + a[7]));
}

// ---------------- reduce 8 chunk partials -> S ----------------
__global__ __launch_bounds__(256) void k_red(const float* __restrict__ Spart,
                                             float* __restrict__ S) {
    int bc = blockIdx.x, dq = blockIdx.y;
    int d = dq * 256 + threadIdx.x;
    float s = 0.f;
#pragma unroll
    for (int ch = 0; ch < NCH; ++ch)
        s += Spart[((size_t)bc * NCH + ch) * Dh + d];
    S[(size_t)bc * Dh + d] = s;
}

// ---- gg2: (S/den)@W_grid.T + b_grid with fused LN-combine epilogue -> out ----
__global__ __launch_bounds__(256) void k_gg2(const float* __restrict__ S,
                                             const float* __restrict__ den,
                                             const uint4* __restrict__ WgH,
                                             const uint4* __restrict__ WgL,
                                             const float* __restrict__ bg,
                                             const float* __restrict__ cn,
                                             const float* __restrict__ lang,
                                             float* __restrict__ out) {
    __shared__ float lds[2][4096];
    int tid = threadIdx.x;
    int wv = tid >> 6, l = tid & 63;
    int m0 = blockIdx.y * 128;
    int dt = blockIdx.x;

    const uint4* pbh = WgH + (size_t)dt * 256 + l;
    const uint4* pbl = WgL + (size_t)dt * 256 + l;

    const float* srcA[4]; int dA[4];
#pragma unroll
    for (int r = 0; r < 4; ++r) {
        int s = r * 256 + tid, row = s >> 3, pos = s & 7;
        int rowg = m0 + row; if (rowg >= Bh * Ch) rowg = Bh * Ch - 1;
        srcA[r] = S + (size_t)rowg * Dh + pos * 4;
        dA[r] = row * 32 + ((pos ^ (row & 7)) << 2);
    }
    int lm = l & 15, lh = l >> 4, r7 = lm & 7;
    int oA[2][2];
#pragma unroll
    for (int rt = 0; rt < 2; ++rt)
#pragma unroll
        for (int j = 0; j < 2; ++j)
            oA[rt][j] = (wv * 32 + rt * 16 + lm) * 32 + (((lh * 2 + j) ^ r7) << 2);

    {
        float4 v0 = *(const float4*)srcA[0];
        float4 v1 = *(const float4*)srcA[1];
        float4 v2 = *(const float4*)srcA[2];
        float4 v3 = *(const float4*)srcA[3];
        *(float4*)&lds[0][dA[0]] = v0;
        *(float4*)&lds[0][dA[1]] = v1;
        *(float4*)&lds[0][dA[2]] = v2;
        *(float4*)&lds[0][dA[3]] = v3;
    }
    __syncthreads();

    f32x4 acc[2][4];
#pragma unroll
    for (int i = 0; i < 2; ++i)
#pragma unroll
        for (int j = 0; j < 4; ++j) acc[i][j] = (f32x4){0.f, 0.f, 0.f, 0.f};

    for (int t = 0; t < 24; ++t) {
        int cur = t & 1;
        float4 p0, p1, p2, p3;
        bool pf = (t < 23);
        if (pf) {
            int o = (t + 1) * 32;
            p0 = *(const float4*)(srcA[0] + o);
            p1 = *(const float4*)(srcA[1] + o);
            p2 = *(const float4*)(srcA[2] + o);
            p3 = *(const float4*)(srcA[3] + o);
        }
        uint4 bh0 = pbh[t * 3072 +   0], bh1 = pbh[t * 3072 +  64];
        uint4 bh2 = pbh[t * 3072 + 128], bh3 = pbh[t * 3072 + 192];
        uint4 bl0 = pbl[t * 3072 +   0], bl1 = pbl[t * 3072 +  64];
        uint4 bl2 = pbl[t * 3072 + 128], bl3 = pbl[t * 3072 + 192];

        const float* L = lds[cur];
        float4 a00 = *(const float4*)&L[oA[0][0]];
        float4 a01 = *(const float4*)&L[oA[0][1]];
        float4 a10 = *(const float4*)&L[oA[1][0]];
        float4 a11 = *(const float4*)&L[oA[1][1]];
        bf16x8 ah0, al0, ah1, al1;
        cvt8(a00, a01, ah0, al0);
        cvt8(a10, a11, ah1, al1);

        uint4 bhu[4] = {bh0, bh1, bh2, bh3};
        uint4 blu[4] = {bl0, bl1, bl2, bl3};
#pragma unroll
        for (int ct = 0; ct < 4; ++ct) {
            U ubh, ubl; ubh.u = bhu[ct]; ubl.u = blu[ct];
            bf16x8 bh = ubh.v, bl = ubl.v;
            acc[0][ct] = __builtin_amdgcn_mfma_f32_16x16x32_bf16(ah0, bh, acc[0][ct], 0, 0, 0);
            acc[0][ct] = __builtin_amdgcn_mfma_f32_16x16x32_bf16(al0, bh, acc[0][ct], 0, 0, 0);
            acc[0][ct] = __builtin_amdgcn_mfma_f32_16x16x32_bf16(ah0, bl, acc[0][ct], 0, 0, 0);
            acc[1][ct] = __builtin_amdgcn_mfma_f32_16x16x32_bf16(ah1, bh, acc[1][ct], 0, 0, 0);
            acc[1][ct] = __builtin_amdgcn_mfma_f32_16x16x32_bf16(al1, bh, acc[1][ct], 0, 0, 0);
            acc[1][ct] = __builtin_amdgcn_mfma_f32_16x16x32_bf16(ah1, bl, acc[1][ct], 0, 0, 0);
        }
        if (pf) {
            float* D = lds[cur ^ 1];
            *(float4*)&D[dA[0]] = p0;
            *(float4*)&D[dA[1]] = p1;
            *(float4*)&D[dA[2]] = p2;
            *(float4*)&D[dA[3]] = p3;
        }
        __syncthreads();
    }

    // fused epilogue: out[b][50+c][d] = cn*lang[b,0,d] + (den>0 ? acc/den + bg[d] : 0)
#pragma unroll
    for (int rt = 0; rt < 2; ++rt) {
#pragma unroll
        for (int r = 0; r < 4; ++r) {
            int row = m0 + wv * 32 + rt * 16 + lh * 4 + r;
            if (row < Bh * Ch) {
                float dv = den[row];
                float inv = (dv > 0.f) ? 1.f / dv : 0.f;
                int bb = row / Ch, cc = row - bb * Ch;
                const float* lrow = lang + (size_t)bb * Lh * Dh;
#pragma unroll
                for (int ct = 0; ct < 4; ++ct) {
                    int d = dt * 64 + ct * 16 + lm;
                    float gm = (dv > 0.f) ? acc[rt][ct][r] * inv + bg[d] : 0.f;
                    out[((size_t)(bb * (Fh + Ch) + Fh + cc)) * Dh + d] =
                        cn[(size_t)row * Dh + d] * lrow[d] + gm;
                }
            }
        }
    }
}

extern "C" void kernel_launch(void* const* d_in, const int* in_sizes, int n_in,
                              void* d_out, int out_size, void* d_ws, size_t ws_size,
                              hipStream_t stream) {
    (void)in_sizes; (void)n_in; (void)out_size; (void)ws_size;
    const float* lang      = (const float*)d_in[0];
    const float* lang_cls  = (const float*)d_in[1];
    const float* frames    = (const float*)d_in[2];
    const float* cands     = (const float*)d_in[3];
    const float* grid_fts  = (const float*)d_in[4];
    const int*   grid_idx  = (const int*)d_in[5];
    const float* W_in      = (const float*)d_in[6];
    const float* W_out     = (const float*)d_in[7];
    const float* W_fc2     = (const float*)d_in[8];
    const float* b_fc2     = (const float*)d_in[9];
    const float* W_text    = (const float*)d_in[10];
    const float* b_text    = (const float*)d_in[11];
    const float* W_grid    = (const float*)d_in[12];
    const float* b_grid    = (const float*)d_in[13];
    const float* W_cand    = (const float*)d_in[14];
    const float* b_cand    = (const float*)d_in[15];
    const float* ln_g      = (const float*)d_in[16];
    const float* ln_b      = (const float*)d_in[17];
    float* out = (float*)d_out;
    float* ws  = (float*)d_ws;

    float*    wbuf  = ws;                        // 160000
    unsigned* m_u   = (unsigned*)(ws + 160000);  // 288
    float*    den   = ws + 160288;               // 288
    int*      cnt   = (int*)(ws + 160576);       // 288
    int*      bn    = (int*)(ws + 160864);       // 589824
    float*    bp    = ws + 750688;               // 589824
    float*    Spart = ws + 1340512;              // 1769472
    float*    cn    = ws + 3109984;              // 221184
    uint4*    textH = (uint4*)(ws + 3331168);    // 196608 floats
    uint4*    textL = (uint4*)(ws + 3527776);    // 196608 floats
    float*    S     = ws + 3724384;              // 221184
    uint4*    WgH   = (uint4*)(ws + 3945568);    // 294912 floats
    uint4*    WgL   = (uint4*)(ws + 4240480);    // 294912 floats
    uint4*    WtH   = (uint4*)(ws + 4535392);    // 294912 floats
    uint4*    WtL   = (uint4*)(ws + 4830304);    // 294912 floats
    float*    Wf2T  = ws + 5125216;              // 37632
    float*    text  = ws + 5162848;              // 393216

    hipLaunchKernelGGL(k_prep,   dim3(1012), dim3(256), 0, stream,
                       W_grid, W_text, W_fc2, cands, W_cand, b_cand, ln_g, ln_b,
                       WgH, WgL, WtH, WtL, Wf2T, cn, m_u, den, cnt);
    hipLaunchKernelGGL(k_tf,     dim3(448), dim3(256), 0, stream,
                       lang, WtH, WtL, b_text, frames, lang_cls, W_in, W_out, Wf2T, b_fc2,
                       text, out);
    hipLaunchKernelGGL(k_tfrag,  dim3(192), dim3(256), 0, stream, text, textH, textL);
    hipLaunchKernelGGL(k_w,      dim3((Nh + 127) / 128, Bh), dim3(256), 0, stream,
                       grid_fts, textH, textL, grid_idx, wbuf, m_u);
    hipLaunchKernelGGL(k_epc,    dim3(79, Bh), dim3(256), 0, stream,
                       wbuf, grid_idx, m_u, den, cnt, bn, bp);
    hipLaunchKernelGGL(k_S3,     dim3(Ch, 3, Bh * NCH), dim3(256), 0, stream,
                       grid_fts, cnt, bn, bp, Spart);
    hipLaunchKernelGGL(k_red,    dim3(Bh * Ch, 3), dim3(256), 0, stream, Spart, S);
    hipLaunchKernelGGL(k_gg2,    dim3(12, 3), dim3(256), 0, stream,
                       S, den, WgH, WgL, b_grid, cn, lang, out);
}

// Round 16
// 226.284 us; speedup vs baseline: 1.4547x; 1.0681x over previous
//
#include <hip/hip_runtime.h>
#include <math.h>

#define Bh 8
#define Lh 64
#define Dh 768
#define Fh 50
#define Ph 49
#define Ah 49
#define Nh 20000
#define Ch 36
#define CAP 2048
#define NCH 8
#define CUTE 2e-6f

typedef __bf16 bf16x8 __attribute__((ext_vector_type(8)));
typedef float f32x4 __attribute__((ext_vector_type(4)));
union U { uint4 u; bf16x8 v; };

__device__ __forceinline__ void cvt2(float a0, float a1, unsigned& h, unsigned& l) {
    unsigned u0 = __float_as_uint(a0), u1 = __float_as_uint(a1);
    unsigned h0 = u0 & 0xFFFF0000u, h1 = u1 & 0xFFFF0000u;
    h = (h0 >> 16) | h1;
    float l0 = a0 - __uint_as_float(h0);
    float l1 = a1 - __uint_as_float(h1);
    l = (__float_as_uint(l0) >> 16) | (__float_as_uint(l1) & 0xFFFF0000u);
}

__device__ __forceinline__ void cvt8(float4 p, float4 q, bf16x8& h8, bf16x8& l8) {
    U h, l;
    cvt2(p.x, p.y, h.u.x, l.u.x);
    cvt2(p.z, p.w, h.u.y, l.u.y);
    cvt2(q.x, q.y, h.u.z, l.u.z);
    cvt2(q.z, q.w, h.u.w, l.u.w);
    h8 = h.v; l8 = l.v;
}

__device__ __forceinline__ float dec_max(unsigned u) {
    if (u == 0u) return 0.f;
    return (u & 0x80000000u) ? __uint_as_float(u ^ 0x80000000u) : __uint_as_float(~u);
}

// ---------------- prep: W_grid/W_text -> fragments | W_fc2 transpose | zero ----------------
__global__ __launch_bounds__(256) void k_prep(const float* __restrict__ Wg,
                                              const float* __restrict__ Wt,
                                              const float* __restrict__ Wf2,
                                              uint4* __restrict__ WgH, uint4* __restrict__ WgL,
                                              uint4* __restrict__ WtH, uint4* __restrict__ WtL,
                                              float* __restrict__ Wf2T,
                                              unsigned* __restrict__ m_u,
                                              float* __restrict__ den,
                                              int* __restrict__ cnt) {
    int bx = blockIdx.x, tid = threadIdx.x;
    if (bx < 576) {
        bool g = bx < 288;
        int gid = (g ? bx : bx - 288) * 256 + tid;   // < 73728
        const float* W = g ? Wg : Wt;
        int l = gid & 63;
        int rest = gid >> 6;
        int ct = rest % 48, ks = rest / 48;
        const float* src = W + (size_t)(ct * 16 + (l & 15)) * Dh + ks * 32 + (l >> 4) * 8;
        float4 p = *(const float4*)src;
        float4 q = *(const float4*)(src + 4);
        U h, lo;
        cvt2(p.x, p.y, h.u.x, lo.u.x);
        cvt2(p.z, p.w, h.u.y, lo.u.y);
        cvt2(q.x, q.y, h.u.z, lo.u.z);
        cvt2(q.z, q.w, h.u.w, lo.u.w);
        if (g) { WgH[gid] = h.u; WgL[gid] = lo.u; }
        else   { WtH[gid] = h.u; WtL[gid] = lo.u; }
    } else if (bx < 723) {
        int i = (bx - 576) * 256 + tid;              // < 37632 = 768*49 exact
        int d = i / 49, j = i - d * 49;
        Wf2T[j * Dh + d] = Wf2[i];
    } else {
        for (int i = tid; i < Bh * Ch; i += 256) { m_u[i] = 0u; den[i] = 0.f; cnt[i] = 0; }
    }
}

// ---------------- tf: [0,48) text MFMA GEMM | [48,448) frames path ----------------
__global__ __launch_bounds__(256) void k_tf(const float* __restrict__ lang,
                                            const uint4* __restrict__ WtH,
                                            const uint4* __restrict__ WtL,
                                            const float* __restrict__ bt,
                                            const float* __restrict__ frames,
                                            const float* __restrict__ lang_cls,
                                            const float* __restrict__ W_in,
                                            const float* __restrict__ W_out,
                                            const float* __restrict__ Wf2T,
                                            const float* __restrict__ b_fc2,
                                            float* __restrict__ text,
                                            float* __restrict__ out) {
    __shared__ float smem[8192];
    int bx = blockIdx.x;
    int tid = threadIdx.x;

    if (bx < 48) {
        float (*lds)[4096] = (float(*)[4096])smem;
        int wv = tid >> 6, l = tid & 63;
        int dt = bx % 12;
        int m0 = (bx / 12) * 128;

        const uint4* pbh = WtH + (size_t)dt * 256 + l;
        const uint4* pbl = WtL + (size_t)dt * 256 + l;

        const float* srcA[4]; int dA[4];
#pragma unroll
        for (int r = 0; r < 4; ++r) {
            int s = r * 256 + tid, row = s >> 3, pos = s & 7;
            srcA[r] = lang + (size_t)(m0 + row) * Dh + pos * 4;
            dA[r] = row * 32 + ((pos ^ (row & 7)) << 2);
        }
        int lm = l & 15, lh = l >> 4, r7 = lm & 7;
        int oA[2][2];
#pragma unroll
        for (int rt = 0; rt < 2; ++rt)
#pragma unroll
            for (int j = 0; j < 2; ++j)
                oA[rt][j] = (wv * 32 + rt * 16 + lm) * 32 + (((lh * 2 + j) ^ r7) << 2);

        {
            float4 v0 = *(const float4*)srcA[0];
            float4 v1 = *(const float4*)srcA[1];
            float4 v2 = *(const float4*)srcA[2];
            float4 v3 = *(const float4*)srcA[3];
            *(float4*)&lds[0][dA[0]] = v0;
            *(float4*)&lds[0][dA[1]] = v1;
            *(float4*)&lds[0][dA[2]] = v2;
            *(float4*)&lds[0][dA[3]] = v3;
        }
        __syncthreads();

        f32x4 acc[2][4];
#pragma unroll
        for (int i = 0; i < 2; ++i)
#pragma unroll
            for (int j = 0; j < 4; ++j) acc[i][j] = (f32x4){0.f, 0.f, 0.f, 0.f};

        for (int t = 0; t < 24; ++t) {
            int cur = t & 1;
            float4 p0, p1, p2, p3;
            bool pf = (t < 23);
            if (pf) {
                int o = (t + 1) * 32;
                p0 = *(const float4*)(srcA[0] + o);
                p1 = *(const float4*)(srcA[1] + o);
                p2 = *(const float4*)(srcA[2] + o);
                p3 = *(const float4*)(srcA[3] + o);
            }
            uint4 bh0 = pbh[t * 3072 +   0], bh1 = pbh[t * 3072 +  64];
            uint4 bh2 = pbh[t * 3072 + 128], bh3 = pbh[t * 3072 + 192];
            uint4 bl0 = pbl[t * 3072 +   0], bl1 = pbl[t * 3072 +  64];
            uint4 bl2 = pbl[t * 3072 + 128], bl3 = pbl[t * 3072 + 192];

            const float* L = lds[cur];
            float4 a00 = *(const float4*)&L[oA[0][0]];
            float4 a01 = *(const float4*)&L[oA[0][1]];
            float4 a10 = *(const float4*)&L[oA[1][0]];
            float4 a11 = *(const float4*)&L[oA[1][1]];
            bf16x8 ah0, al0, ah1, al1;
            cvt8(a00, a01, ah0, al0);
            cvt8(a10, a11, ah1, al1);

            uint4 bhu[4] = {bh0, bh1, bh2, bh3};
            uint4 blu[4] = {bl0, bl1, bl2, bl3};
#pragma unroll
            for (int ct = 0; ct < 4; ++ct) {
                U ubh, ubl; ubh.u = bhu[ct]; ubl.u = blu[ct];
                bf16x8 bh = ubh.v, bl = ubl.v;
                acc[0][ct] = __builtin_amdgcn_mfma_f32_16x16x32_bf16(ah0, bh, acc[0][ct], 0, 0, 0);
                acc[0][ct] = __builtin_amdgcn_mfma_f32_16x16x32_bf16(al0, bh, acc[0][ct], 0, 0, 0);
                acc[0][ct] = __builtin_amdgcn_mfma_f32_16x16x32_bf16(ah0, bl, acc[0][ct], 0, 0, 0);
                acc[1][ct] = __builtin_amdgcn_mfma_f32_16x16x32_bf16(ah1, bh, acc[1][ct], 0, 0, 0);
                acc[1][ct] = __builtin_amdgcn_mfma_f32_16x16x32_bf16(al1, bh, acc[1][ct], 0, 0, 0);
                acc[1][ct] = __builtin_amdgcn_mfma_f32_16x16x32_bf16(ah1, bl, acc[1][ct], 0, 0, 0);
            }
            if (pf) {
                float* D = lds[cur ^ 1];
                *(float4*)&D[dA[0]] = p0;
                *(float4*)&D[dA[1]] = p1;
                *(float4*)&D[dA[2]] = p2;
                *(float4*)&D[dA[3]] = p3;
            }
            __syncthreads();
        }

#pragma unroll
        for (int rt = 0; rt < 2; ++rt) {
#pragma unroll
            for (int r = 0; r < 4; ++r) {
                int row = m0 + wv * 32 + rt * 16 + lh * 4 + r;
#pragma unroll
                for (int ct = 0; ct < 4; ++ct) {
                    int d = dt * 64 + ct * 16 + lm;
                    text[(size_t)row * Dh + d] = acc[rt][ct][r] + bt[d];
                }
            }
        }
    } else {
        int fid = bx - 48;
        int b = fid / Fh, f = fid % Fh;
        float* fr = smem;            // 2401
        float* tg = smem + 2401;     // 49
        float* cl = smem + 2450;     // 49
        float* at = smem + 2499;     // 49
        float* wc = smem + 2548;     // 49
        float* af = smem + 2597;     // 49
        const float* fp = frames + ((size_t)(b * Fh + f)) * (Ph * Ah);
        for (int i = tid; i < Ph * Ah; i += 256) fr[i] = fp[i];
        if (tid < Ah) {
            cl[tid] = lang_cls[b * Ah + tid];
            float s = 0.f;
            for (int k = 0; k < Ah; ++k) s += lang_cls[b * Ah + k] * W_in[tid * Ah + k];
            tg[tid] = s;
        }
        __syncthreads();
        if (tid < Ph) {
            float s = 0.f;
            for (int a = 0; a < Ah; ++a) s += fr[tid * Ah + a] * tg[a];
            at[tid] = s;
        }
        __syncthreads();
        if (tid < 64) {
            float raw = (tid < Ph) ? at[tid] : -3.4e38f;
            float v = raw;
            for (int m = 32; m; m >>= 1) v = fmaxf(v, __shfl_xor(v, m));
            float e = (tid < Ph) ? expf(raw - v) : 0.f;
            float s = e;
            for (int m = 32; m; m >>= 1) s += __shfl_xor(s, m);
            if (tid < Ph) at[tid] = e / s;
        }
        __syncthreads();
        if (tid < Ah) {
            float s = 0.f;
            for (int p = 0; p < Ph; ++p) s += at[p] * fr[p * Ah + tid];
            wc[tid] = s;
        }
        __syncthreads();
        if (tid < Ah) {
            float s = 0.f;
            for (int a = 0; a < Ah; ++a)
                s += wc[a] * W_out[tid * (2 * Ah) + a] + cl[a] * W_out[tid * (2 * Ah) + Ah + a];
            af[tid] = tanhf(s);
        }
        __syncthreads();
        for (int d = tid; d < Dh; d += 256) {
            float s = b_fc2[d];
            for (int j = 0; j < Ah; ++j) s += af[j] * Wf2T[j * Dh + d];
            out[((size_t)(b * (Fh + Ch) + f)) * Dh + d] = s;
        }
    }
}

// ---------------- text -> fragment-major bf16 hi/lo (for k_w's B operand) ----------------
__global__ __launch_bounds__(256) void k_tfrag(const float* __restrict__ text,
                                               uint4* __restrict__ textH,
                                               uint4* __restrict__ textL) {
    int gid = blockIdx.x * 256 + threadIdx.x;  // 192*256 = 49152 exact
    int l  = gid & 63;
    int ct = (gid >> 6) & 3;
    int bk = gid >> 8;             // b*24 + ks
    int b  = bk / 24, ks = bk % 24;
    const float* src = text + ((size_t)(b * Lh + ct * 16 + (l & 15))) * Dh
                     + ks * 32 + (l >> 4) * 8;
    float4 p = *(const float4*)src;
    float4 q = *(const float4*)(src + 4);
    U h, lo;
    cvt2(p.x, p.y, h.u.x, lo.u.x);
    cvt2(p.z, p.w, h.u.y, lo.u.y);
    cvt2(q.x, q.y, h.u.z, lo.u.z);
    cvt2(q.z, q.w, h.u.w, lo.u.w);
    textH[gid] = h.u;
    textL[gid] = lo.u;
}

// ---------------- w[b,n]: A via dbuf LDS (XOR swizzle), B pre-converted from L2 ----------
__global__ __launch_bounds__(256) void k_w(const float* __restrict__ grid,
                                           const uint4* __restrict__ textH,
                                           const uint4* __restrict__ textL,
                                           const int* __restrict__ gi,
                                           float* __restrict__ w,
                                           unsigned* __restrict__ m_u) {
    __shared__ float lds[2][4096];
    __shared__ unsigned mu[Ch];
    int b = blockIdx.y;
    int tid = threadIdx.x;
    int wv = tid >> 6, l = tid & 63;
    int n0 = blockIdx.x * 128;
    if (tid < Ch) mu[tid] = 0u;

    const float* gb = grid + (size_t)b * Nh * Dh;
    const uint4* pbh = textH + (size_t)b * 6144 + l;
    const uint4* pbl = textL + (size_t)b * 6144 + l;

    const float* srcA[4]; int dA[4];
#pragma unroll
    for (int r = 0; r < 4; ++r) {
        int s = r * 256 + tid, row = s >> 3, pos = s & 7;
        int rowg = n0 + row; if (rowg >= Nh) rowg = Nh - 1;
        srcA[r] = gb + (size_t)rowg * Dh + pos * 4;
        dA[r] = row * 32 + ((pos ^ (row & 7)) << 2);
    }
    int lm = l & 15, lh = l >> 4, r7 = lm & 7;
    int oA[2][2];
#pragma unroll
    for (int rt = 0; rt < 2; ++rt)
#pragma unroll
        for (int j = 0; j < 2; ++j)
            oA[rt][j] = (wv * 32 + rt * 16 + lm) * 32 + (((lh * 2 + j) ^ r7) << 2);

    {
        float4 v0 = *(const float4*)srcA[0];
        float4 v1 = *(const float4*)srcA[1];
        float4 v2 = *(const float4*)srcA[2];
        float4 v3 = *(const float4*)srcA[3];
        *(float4*)&lds[0][dA[0]] = v0;
        *(float4*)&lds[0][dA[1]] = v1;
        *(float4*)&lds[0][dA[2]] = v2;
        *(float4*)&lds[0][dA[3]] = v3;
    }
    __syncthreads();

    f32x4 acc[2][4];
#pragma unroll
    for (int i = 0; i < 2; ++i)
#pragma unroll
        for (int j = 0; j < 4; ++j) acc[i][j] = (f32x4){0.f, 0.f, 0.f, 0.f};

    for (int t = 0; t < 24; ++t) {
        int cur = t & 1;
        float4 p0, p1, p2, p3;
        bool pf = (t < 23);
        if (pf) {
            int o = (t + 1) * 32;
            p0 = *(const float4*)(srcA[0] + o);
            p1 = *(const float4*)(srcA[1] + o);
            p2 = *(const float4*)(srcA[2] + o);
            p3 = *(const float4*)(srcA[3] + o);
        }
        uint4 bh0 = pbh[t * 256 +   0], bh1 = pbh[t * 256 +  64];
        uint4 bh2 = pbh[t * 256 + 128], bh3 = pbh[t * 256 + 192];
        uint4 bl0 = pbl[t * 256 +   0], bl1 = pbl[t * 256 +  64];
        uint4 bl2 = pbl[t * 256 + 128], bl3 = pbl[t * 256 + 192];

        const float* L = lds[cur];
        float4 a00 = *(const float4*)&L[oA[0][0]];
        float4 a01 = *(const float4*)&L[oA[0][1]];
        float4 a10 = *(const float4*)&L[oA[1][0]];
        float4 a11 = *(const float4*)&L[oA[1][1]];
        bf16x8 ah0, al0, ah1, al1;
        cvt8(a00, a01, ah0, al0);
        cvt8(a10, a11, ah1, al1);

        uint4 bhu[4] = {bh0, bh1, bh2, bh3};
        uint4 blu[4] = {bl0, bl1, bl2, bl3};
#pragma unroll
        for (int ct = 0; ct < 4; ++ct) {
            U ubh, ubl; ubh.u = bhu[ct]; ubl.u = blu[ct];
            bf16x8 bh = ubh.v, bl = ubl.v;
            acc[0][ct] = __builtin_amdgcn_mfma_f32_16x16x32_bf16(ah0, bh, acc[0][ct], 0, 0, 0);
            acc[0][ct] = __builtin_amdgcn_mfma_f32_16x16x32_bf16(al0, bh, acc[0][ct], 0, 0, 0);
            acc[0][ct] = __builtin_amdgcn_mfma_f32_16x16x32_bf16(ah0, bl, acc[0][ct], 0, 0, 0);
            acc[1][ct] = __builtin_amdgcn_mfma_f32_16x16x32_bf16(ah1, bh, acc[1][ct], 0, 0, 0);
            acc[1][ct] = __builtin_amdgcn_mfma_f32_16x16x32_bf16(al1, bh, acc[1][ct], 0, 0, 0);
            acc[1][ct] = __builtin_amdgcn_mfma_f32_16x16x32_bf16(ah1, bl, acc[1][ct], 0, 0, 0);
        }
        if (pf) {
            float* D = lds[cur ^ 1];
            *(float4*)&D[dA[0]] = p0;
            *(float4*)&D[dA[1]] = p1;
            *(float4*)&D[dA[2]] = p2;
            *(float4*)&D[dA[3]] = p3;
        }
        __syncthreads();
    }

#pragma unroll
    for (int rt = 0; rt < 2; ++rt) {
        float m[4];
#pragma unroll
        for (int r = 0; r < 4; ++r) {
            m[r] = fmaxf(fmaxf(acc[rt][0][r], acc[rt][1][r]),
                         fmaxf(acc[rt][2][r], acc[rt][3][r]));
            m[r] = fmaxf(m[r], __shfl_xor(m[r], 1));
            m[r] = fmaxf(m[r], __shfl_xor(m[r], 2));
            m[r] = fmaxf(m[r], __shfl_xor(m[r], 4));
            m[r] = fmaxf(m[r], __shfl_xor(m[r], 8));
        }
        if (lm == 0) {
#pragma unroll
            for (int r = 0; r < 4; ++r) {
                int row = n0 + wv * 32 + rt * 16 + lh * 4 + r;
                if (row < Nh) {
                    w[b * Nh + row] = m[r];
                    unsigned u = __float_as_uint(m[r]);
                    u = (u & 0x80000000u) ? ~u : (u | 0x80000000u);
                    atomicMax(&mu[gi[b * Nh + row]], u);
                }
            }
        }
    }
    __syncthreads();
    if (tid < Ch && mu[tid]) atomicMax(&m_u[b * Ch + tid], mu[tid]);
}

// ---------------- e = exp(w - m): den-accumulate + compaction ----------------
__global__ __launch_bounds__(256) void k_epc(const float* __restrict__ w,
                                             const int* __restrict__ gi,
                                             const unsigned* __restrict__ m_u,
                                             float* __restrict__ den,
                                             int* __restrict__ cnt,
                                             int* __restrict__ bn,
                                             float* __restrict__ bp) {
    int b = blockIdx.y;
    int n = blockIdx.x * 256 + threadIdx.x;
    __shared__ float dn[Ch];
    if (threadIdx.x < Ch) dn[threadIdx.x] = 0.f;
    __syncthreads();
    if (n < Nh) {
        int c = gi[b * Nh + n];
        float e = expf(w[b * Nh + n] - dec_max(m_u[b * Ch + c]));
        atomicAdd(&dn[c], e);
        if (e > CUTE) {
            int pos = atomicAdd(&cnt[b * Ch + c], 1);
            if (pos < CAP) {
                bn[(b * Ch + c) * CAP + pos] = n;
                bp[(b * Ch + c) * CAP + pos] = e;
            }
        }
    }
    __syncthreads();
    if (threadIdx.x < Ch && dn[threadIdx.x] != 0.f)
        atomicAdd(&den[b * Ch + threadIdx.x], dn[threadIdx.x]);
}

// ---------------- chunked segment weighted sums -> Spart[b][c][ch][d] ----------------
__global__ __launch_bounds__(256) void k_S3(const float* __restrict__ grid,
                                            const int* __restrict__ cnt,
                                            const int* __restrict__ bn,
                                            const float* __restrict__ bp,
                                            float* __restrict__ Spart) {
    int c = blockIdx.x, dq = blockIdx.y;
    int b = blockIdx.z >> 3, ch = blockIdx.z & 7;
    int d = dq * 256 + threadIdx.x;
    int len = cnt[b * Ch + c]; if (len > CAP) len = CAP;
    int i0 = ch * (CAP / NCH);
    int i1 = i0 + (CAP / NCH); if (i1 > len) i1 = len;
    size_t base = (size_t)(b * Ch + c) * CAP;
    size_t po = ((size_t)(b * Ch + c) * NCH + ch) * Dh + d;
    const float* gb = grid + (size_t)b * Nh * Dh + d;
    float a[8] = {0.f, 0.f, 0.f, 0.f, 0.f, 0.f, 0.f, 0.f};
    int i = i0;
    for (; i + 8 <= i1; i += 8) {
        int nn[8]; float pp[8];
#pragma unroll
        for (int j = 0; j < 8; ++j) { nn[j] = bn[base + i + j]; pp[j] = bp[base + i + j]; }
#pragma unroll
        for (int j = 0; j < 8; ++j) a[j] += pp[j] * gb[(size_t)nn[j] * Dh];
    }
    for (; i < i1; ++i) a[0] += bp[base + i] * gb[(size_t)bn[base + i] * Dh];
    Spart[po] = ((a[0] + a[1]) + (a[2] + a[3])) + ((a[4] + a[5]) + (a[6] + a[7]));
}

// ---------------- reduce 8 chunk partials -> S ----------------
__global__ __launch_bounds__(256) void k_red(const float* __restrict__ Spart,
                                             float* __restrict__ S) {
    int bc = blockIdx.x, dq = blockIdx.y;
    int d = dq * 256 + threadIdx.x;
    float s = 0.f;
#pragma unroll
    for (int ch = 0; ch < NCH; ++ch)
        s += Spart[((size_t)bc * NCH + ch) * Dh + d];
    S[(size_t)bc * Dh + d] = s;
}

// ---------------- G = (S/den) @ W_grid.T + b_grid via split-bf16 MFMA ----------------
__global__ __launch_bounds__(256) void k_gg2(const float* __restrict__ S,
                                             const float* __restrict__ den,
                                             const uint4* __restrict__ WgH,
                                             const uint4* __restrict__ WgL,
                                             const float* __restrict__ bg,
                                             float* __restrict__ G) {
    __shared__ float lds[2][4096];
    int tid = threadIdx.x;
    int wv = tid >> 6, l = tid & 63;
    int m0 = blockIdx.y * 128;
    int dt = blockIdx.x;

    const uint4* pbh = WgH + (size_t)dt * 256 + l;
    const uint4* pbl = WgL + (size_t)dt * 256 + l;

    const float* srcA[4]; int dA[4];
#pragma unroll
    for (int r = 0; r < 4; ++r) {
        int s = r * 256 + tid, row = s >> 3, pos = s & 7;
        int rowg = m0 + row; if (rowg >= Bh * Ch) rowg = Bh * Ch - 1;
        srcA[r] = S + (size_t)rowg * Dh + pos * 4;
        dA[r] = row * 32 + ((pos ^ (row & 7)) << 2);
    }
    int lm = l & 15, lh = l >> 4, r7 = lm & 7;
    int oA[2][2];
#pragma unroll
    for (int rt = 0; rt < 2; ++rt)
#pragma unroll
        for (int j = 0; j < 2; ++j)
            oA[rt][j] = (wv * 32 + rt * 16 + lm) * 32 + (((lh * 2 + j) ^ r7) << 2);

    {
        float4 v0 = *(const float4*)srcA[0];
        float4 v1 = *(const float4*)srcA[1];
        float4 v2 = *(const float4*)srcA[2];
        float4 v3 = *(const float4*)srcA[3];
        *(float4*)&lds[0][dA[0]] = v0;
        *(float4*)&lds[0][dA[1]] = v1;
        *(float4*)&lds[0][dA[2]] = v2;
        *(float4*)&lds[0][dA[3]] = v3;
    }
    __syncthreads();

    f32x4 acc[2][4];
#pragma unroll
    for (int i = 0; i < 2; ++i)
#pragma unroll
        for (int j = 0; j < 4; ++j) acc[i][j] = (f32x4){0.f, 0.f, 0.f, 0.f};

    for (int t = 0; t < 24; ++t) {
        int cur = t & 1;
        float4 p0, p1, p2, p3;
        bool pf = (t < 23);
        if (pf) {
            int o = (t + 1) * 32;
            p0 = *(const float4*)(srcA[0] + o);
            p1 = *(const float4*)(srcA[1] + o);
            p2 = *(const float4*)(srcA[2] + o);
            p3 = *(const float4*)(srcA[3] + o);
        }
        uint4 bh0 = pbh[t * 3072 +   0], bh1 = pbh[t * 3072 +  64];
        uint4 bh2 = pbh[t * 3072 + 128], bh3 = pbh[t * 3072 + 192];
        uint4 bl0 = pbl[t * 3072 +   0], bl1 = pbl[t * 3072 +  64];
        uint4 bl2 = pbl[t * 3072 + 128], bl3 = pbl[t * 3072 + 192];

        const float* L = lds[cur];
        float4 a00 = *(const float4*)&L[oA[0][0]];
        float4 a01 = *(const float4*)&L[oA[0][1]];
        float4 a10 = *(const float4*)&L[oA[1][0]];
        float4 a11 = *(const float4*)&L[oA[1][1]];
        bf16x8 ah0, al0, ah1, al1;
        cvt8(a00, a01, ah0, al0);
        cvt8(a10, a11, ah1, al1);

        uint4 bhu[4] = {bh0, bh1, bh2, bh3};
        uint4 blu[4] = {bl0, bl1, bl2, bl3};
#pragma unroll
        for (int ct = 0; ct < 4; ++ct) {
            U ubh, ubl; ubh.u = bhu[ct]; ubl.u = blu[ct];
            bf16x8 bh = ubh.v, bl = ubl.v;
            acc[0][ct] = __builtin_amdgcn_mfma_f32_16x16x32_bf16(ah0, bh, acc[0][ct], 0, 0, 0);
            acc[0][ct] = __builtin_amdgcn_mfma_f32_16x16x32_bf16(al0, bh, acc[0][ct], 0, 0, 0);
            acc[0][ct] = __builtin_amdgcn_mfma_f32_16x16x32_bf16(ah0, bl, acc[0][ct], 0, 0, 0);
            acc[1][ct] = __builtin_amdgcn_mfma_f32_16x16x32_bf16(ah1, bh, acc[1][ct], 0, 0, 0);
            acc[1][ct] = __builtin_amdgcn_mfma_f32_16x16x32_bf16(al1, bh, acc[1][ct], 0, 0, 0);
            acc[1][ct] = __builtin_amdgcn_mfma_f32_16x16x32_bf16(ah1, bl, acc[1][ct], 0, 0, 0);
        }
        if (pf) {
            float* D = lds[cur ^ 1];
            *(float4*)&D[dA[0]] = p0;
            *(float4*)&D[dA[1]] = p1;
            *(float4*)&D[dA[2]] = p2;
            *(float4*)&D[dA[3]] = p3;
        }
        __syncthreads();
    }

#pragma unroll
    for (int rt = 0; rt < 2; ++rt) {
#pragma unroll
        for (int r = 0; r < 4; ++r) {
            int row = m0 + wv * 32 + rt * 16 + lh * 4 + r;
            if (row < Bh * Ch) {
                float dv = den[row];
                float inv = (dv > 0.f) ? 1.f / dv : 0.f;
#pragma unroll
                for (int ct = 0; ct < 4; ++ct) {
                    int d = dt * 64 + ct * 16 + lm;
                    G[(size_t)row * Dh + d] = acc[rt][ct][r] * inv + bg[d];
                }
            }
        }
    }
}

// ---------------- final: candidate LN + combine ----------------
__global__ __launch_bounds__(256) void k_final(const float* __restrict__ G,
                                               const float* __restrict__ den,
                                               const float* __restrict__ cands,
                                               const float* __restrict__ W_cand,
                                               const float* __restrict__ b_cand,
                                               const float* __restrict__ ln_g,
                                               const float* __restrict__ ln_b,
                                               const float* __restrict__ lang,
                                               float* __restrict__ out) {
    int b = blockIdx.x / Ch, c = blockIdx.x % Ch;
    int tid = threadIdx.x;
    __shared__ float cv[Dh];
    __shared__ float red[8];
    __shared__ float mu_s, rs_s;
    float cx = cands[(b * Ch + c) * 2 + 0], cy = cands[(b * Ch + c) * 2 + 1];
    for (int d = tid; d < Dh; d += 256)
        cv[d] = W_cand[d * 2] * cx + W_cand[d * 2 + 1] * cy + b_cand[d];
    __syncthreads();
    float ls = 0.f;
    for (int d = tid; d < Dh; d += 256) ls += cv[d];
    for (int m = 32; m; m >>= 1) ls += __shfl_xor(ls, m);
    if ((tid & 63) == 0) red[tid >> 6] = ls;
    __syncthreads();
    if (tid == 0) mu_s = (red[0] + red[1] + red[2] + red[3]) * (1.f / Dh);
    __syncthreads();
    float mu = mu_s;
    float lv = 0.f;
    for (int d = tid; d < Dh; d += 256) { float t = cv[d] - mu; lv += t * t; }
    for (int m = 32; m; m >>= 1) lv += __shfl_xor(lv, m);
    if ((tid & 63) == 0) red[4 + (tid >> 6)] = lv;
    __syncthreads();
    if (tid == 0) rs_s = rsqrtf((red[4] + red[5] + red[6] + red[7]) * (1.f / Dh) + 1e-12f);
    __syncthreads();
    float rs = rs_s;
    float dv = den[b * Ch + c];
#pragma unroll
    for (int j = 0; j < 3; ++j) {
        int d = tid + j * 256;
        float gm = (dv > 0.f) ? G[(size_t)(b * Ch + c) * Dh + d] : 0.f;
        float cn = (cv[d] - mu) * rs * ln_g[d] + ln_b[d];
        out[((size_t)(b * (Fh + Ch) + Fh + c)) * Dh + d] =
            cn * lang[((size_t)b * Lh) * Dh + d] + gm;
    }
}

extern "C" void kernel_launch(void* const* d_in, const int* in_sizes, int n_in,
                              void* d_out, int out_size, void* d_ws, size_t ws_size,
                              hipStream_t stream) {
    (void)in_sizes; (void)n_in; (void)out_size; (void)ws_size;
    const float* lang      = (const float*)d_in[0];
    const float* lang_cls  = (const float*)d_in[1];
    const float* frames    = (const float*)d_in[2];
    const float* cands     = (const float*)d_in[3];
    const float* grid_fts  = (const float*)d_in[4];
    const int*   grid_idx  = (const int*)d_in[5];
    const float* W_in      = (const float*)d_in[6];
    const float* W_out     = (const float*)d_in[7];
    const float* W_fc2     = (const float*)d_in[8];
    const float* b_fc2     = (const float*)d_in[9];
    const float* W_text    = (const float*)d_in[10];
    const float* b_text    = (const float*)d_in[11];
    const float* W_grid    = (const float*)d_in[12];
    const float* b_grid    = (const float*)d_in[13];
    const float* W_cand    = (const float*)d_in[14];
    const float* b_cand    = (const float*)d_in[15];
    const float* ln_g      = (const float*)d_in[16];
    const float* ln_b      = (const float*)d_in[17];
    float* out = (float*)d_out;
    float* ws  = (float*)d_ws;

    float*    wbuf  = ws;                        // 160000
    unsigned* m_u   = (unsigned*)(ws + 160000);  // 288
    float*    den   = ws + 160288;               // 288
    int*      cnt   = (int*)(ws + 160576);       // 288
    int*      bn    = (int*)(ws + 160864);       // 589824
    float*    bp    = ws + 750688;               // 589824
    float*    Spart = ws + 1340512;              // 1769472
    float*    G     = ws + 3109984;              // 221184
    uint4*    textH = (uint4*)(ws + 3331168);    // 196608 floats
    uint4*    textL = (uint4*)(ws + 3527776);    // 196608 floats
    float*    S     = ws + 3724384;              // 221184
    uint4*    WgH   = (uint4*)(ws + 3945568);    // 294912 floats
    uint4*    WgL   = (uint4*)(ws + 4240480);    // 294912 floats
    uint4*    WtH   = (uint4*)(ws + 4535392);    // 294912 floats
    uint4*    WtL   = (uint4*)(ws + 4830304);    // 294912 floats
    float*    Wf2T  = ws + 5125216;              // 37632
    float*    text  = ws + 5162848;              // 393216

    hipLaunchKernelGGL(k_prep,   dim3(724), dim3(256), 0, stream,
                       W_grid, W_text, W_fc2, WgH, WgL, WtH, WtL, Wf2T, m_u, den, cnt);
    hipLaunchKernelGGL(k_tf,     dim3(448), dim3(256), 0, stream,
                       lang, WtH, WtL, b_text, frames, lang_cls, W_in, W_out, Wf2T, b_fc2,
                       text, out);
    hipLaunchKernelGGL(k_tfrag,  dim3(192), dim3(256), 0, stream, text, textH, textL);
    hipLaunchKernelGGL(k_w,      dim3((Nh + 127) / 128, Bh), dim3(256), 0, stream,
                       grid_fts, textH, textL, grid_idx, wbuf, m_u);
    hipLaunchKernelGGL(k_epc,    dim3(79, Bh), dim3(256), 0, stream,
                       wbuf, grid_idx, m_u, den, cnt, bn, bp);
    hipLaunchKernelGGL(k_S3,     dim3(Ch, 3, Bh * NCH), dim3(256), 0, stream,
                       grid_fts, cnt, bn, bp, Spart);
    hipLaunchKernelGGL(k_red,    dim3(Bh * Ch, 3), dim3(256), 0, stream, Spart, S);
    hipLaunchKernelGGL(k_gg2,    dim3(12, 3), dim3(256), 0, stream,
                       S, den, WgH, WgL, b_grid, G);
    hipLaunchKernelGGL(k_final,  dim3(Bh * Ch), dim3(256), 0, stream,
                       G, den, cands, W_cand, b_cand, ln_g, ln_b, lang, out);
}